// Round 1
// baseline (379.828 us; speedup 1.0000x reference)
//
#include <hip/hip_runtime.h>
#include <hip/hip_bf16.h>

typedef unsigned short u16;
typedef __attribute__((ext_vector_type(8))) short short8;
typedef __attribute__((ext_vector_type(4))) float f32x4;

__device__ __forceinline__ u16 f2bf(float f) {
    union { float f; unsigned u; } v; v.f = f;
    unsigned r = v.u + 0x7fffu + ((v.u >> 16) & 1u);
    return (u16)(r >> 16);
}
__device__ __forceinline__ float bf2f(u16 h) {
    union { unsigned u; float f; } v; v.u = ((unsigned)h) << 16;
    return v.f;
}

// ---------------------------------------------------------------------------
// Shared 128x128x512 MFMA core: A [128,512] bf16 row-major, B^T [128,512] bf16
// row-major (i.e. computes A . B^T). 4 waves, each 64x64 (4x4 tiles of
// 16x16x32). LDS rows padded 32->40 elems (80B stride keeps 16B align,
// 2-way bank aliasing = free).
// ---------------------------------------------------------------------------
__device__ __forceinline__ void gemm512(const u16* __restrict__ A,
                                        const u16* __restrict__ B,
                                        u16 (*As)[40], u16 (*Bs)[40],
                                        f32x4 acc[4][4], int tid) {
    const int r = tid >> 2, c = (tid & 3) * 8;
    const int lane = tid & 63, quad = lane >> 4, l15 = lane & 15;
    const int wm = tid >> 7, wn = (tid >> 6) & 1;
    for (int k0 = 0; k0 < 512; k0 += 32) {
        __syncthreads();
        *(uint4*)&As[r][c]      = *(const uint4*)&A[r * 512 + k0 + c];
        *(uint4*)&As[r + 64][c] = *(const uint4*)&A[(r + 64) * 512 + k0 + c];
        *(uint4*)&Bs[r][c]      = *(const uint4*)&B[r * 512 + k0 + c];
        *(uint4*)&Bs[r + 64][c] = *(const uint4*)&B[(r + 64) * 512 + k0 + c];
        __syncthreads();
        short8 af[4], bfr[4];
#pragma unroll
        for (int i = 0; i < 4; i++)
            af[i] = *(const short8*)&As[wm * 64 + i * 16 + l15][quad * 8];
#pragma unroll
        for (int j = 0; j < 4; j++)
            bfr[j] = *(const short8*)&Bs[wn * 64 + j * 16 + l15][quad * 8];
#pragma unroll
        for (int i = 0; i < 4; i++)
#pragma unroll
            for (int j = 0; j < 4; j++)
                acc[i][j] = __builtin_amdgcn_mfma_f32_16x16x32_bf16(
                    af[i], bfr[j], acc[i][j], 0, 0, 0);
    }
}

// ---------------------------------------------------------------------------
// Prep kernels
// ---------------------------------------------------------------------------
__global__ void convert_x(const float* __restrict__ X, u16* __restrict__ Xb) {
    int idx = (blockIdx.x * 256 + threadIdx.x) * 4;
    float4 v = *(const float4*)&X[idx];
    ushort4 o;
    o.x = f2bf(v.x); o.y = f2bf(v.y); o.z = f2bf(v.z); o.w = f2bf(v.w);
    *(ushort4*)&Xb[idx] = o;
}

__global__ void transpose_w(const float* __restrict__ W0, const float* __restrict__ W1,
                            const float* __restrict__ W2, const float* __restrict__ W3,
                            u16* __restrict__ T0, u16* __restrict__ T1,
                            u16* __restrict__ T2, u16* __restrict__ T3) {
    const float* src; u16* dst;
    switch (blockIdx.z) {
        case 0: src = W0; dst = T0; break;
        case 1: src = W1; dst = T1; break;
        case 2: src = W2; dst = T2; break;
        default: src = W3; dst = T3; break;
    }
    __shared__ float tile[32][33];
    int bo_ = blockIdx.x * 32;  // output-channel offset
    int bi  = blockIdx.y * 32;  // input-channel offset
#pragma unroll
    for (int t = 0; t < 4; t++) {
        int i = bi + threadIdx.y + t * 8;
        tile[threadIdx.y + t * 8][threadIdx.x] = src[i * 512 + bo_ + threadIdx.x];
    }
    __syncthreads();
#pragma unroll
    for (int t = 0; t < 4; t++) {
        int o = bo_ + threadIdx.y + t * 8;
        dst[o * 512 + bi + threadIdx.x] = f2bf(tile[threadIdx.x][threadIdx.y + t * 8]);
    }
}

// ---------------------------------------------------------------------------
// QKV projection: C[m,n] = A[m,:] . Wt[n,:] + bias[n], bf16 out
// ---------------------------------------------------------------------------
__global__ __launch_bounds__(256) void gemm_bias_bf16(
    const u16* __restrict__ A, const u16* __restrict__ Bt,
    const float* __restrict__ bias, u16* __restrict__ C) {
    __shared__ __align__(16) u16 As[128][40];
    __shared__ __align__(16) u16 Bs[128][40];
    int tid = threadIdx.x;
    int m0 = blockIdx.x * 128, n0 = blockIdx.y * 128;
    f32x4 acc[4][4];
#pragma unroll
    for (int i = 0; i < 4; i++)
#pragma unroll
        for (int j = 0; j < 4; j++) acc[i][j] = (f32x4){0.f, 0.f, 0.f, 0.f};
    gemm512(A + (size_t)m0 * 512, Bt + (size_t)n0 * 512, As, Bs, acc, tid);
    int lane = tid & 63, quad = lane >> 4, l15 = lane & 15;
    int wm = tid >> 7, wn = (tid >> 6) & 1;
#pragma unroll
    for (int j = 0; j < 4; j++) {
        int n = n0 + wn * 64 + j * 16 + l15;
        float bv = bias[n];
#pragma unroll
        for (int i = 0; i < 4; i++)
#pragma unroll
            for (int rg = 0; rg < 4; rg++) {
                int m = m0 + wm * 64 + i * 16 + quad * 4 + rg;
                C[(size_t)m * 512 + n] = f2bf(acc[i][j][rg] + bv);
            }
    }
}

// ---------------------------------------------------------------------------
// Pass 1: per-row running max / sum-exp over an n-chunk of 1024 cols.
// grid (mblk=32, nch=4, b=2)
// ---------------------------------------------------------------------------
__global__ __launch_bounds__(256) void attn_pass1(
    const u16* __restrict__ Qb, const u16* __restrict__ Kb,
    float2* __restrict__ statsP) {
    __shared__ __align__(16) u16 As[128][40];
    __shared__ __align__(16) u16 Bs[128][40];
    __shared__ float redM[2][128], redS[2][128], rowMn[128], runM[128], runL[128];
    int tid = threadIdx.x;
    int mblk = blockIdx.x, nch = blockIdx.y, b = blockIdx.z;
    const u16* Q = Qb + ((size_t)(b * 4096 + mblk * 128)) * 512;
    if (tid < 128) { runM[tid] = -INFINITY; runL[tid] = 0.f; }
    int lane = tid & 63, quad = lane >> 4, l15 = lane & 15;
    int wm = tid >> 7, wn = (tid >> 6) & 1;
    for (int nt = 0; nt < 8; nt++) {
        const u16* K = Kb + ((size_t)(b * 4096 + nch * 1024 + nt * 128)) * 512;
        f32x4 acc[4][4];
#pragma unroll
        for (int i = 0; i < 4; i++)
#pragma unroll
            for (int j = 0; j < 4; j++) acc[i][j] = (f32x4){0.f, 0.f, 0.f, 0.f};
        gemm512(Q, K, As, Bs, acc, tid);  // first internal barrier covers init
#pragma unroll
        for (int i = 0; i < 4; i++)
#pragma unroll
            for (int rg = 0; rg < 4; rg++) {
                float v = fmaxf(fmaxf(acc[i][0][rg], acc[i][1][rg]),
                                fmaxf(acc[i][2][rg], acc[i][3][rg]));
                v = fmaxf(v, __shfl_xor(v, 1));
                v = fmaxf(v, __shfl_xor(v, 2));
                v = fmaxf(v, __shfl_xor(v, 4));
                v = fmaxf(v, __shfl_xor(v, 8));
                if (l15 == 0) redM[wn][wm * 64 + i * 16 + quad * 4 + rg] = v;
            }
        __syncthreads();
        if (tid < 128)
            rowMn[tid] = fmaxf(runM[tid], fmaxf(redM[0][tid], redM[1][tid]));
        __syncthreads();
#pragma unroll
        for (int i = 0; i < 4; i++)
#pragma unroll
            for (int rg = 0; rg < 4; rg++) {
                float mx = rowMn[wm * 64 + i * 16 + quad * 4 + rg];
                float s = __expf(acc[i][0][rg] - mx) + __expf(acc[i][1][rg] - mx) +
                          __expf(acc[i][2][rg] - mx) + __expf(acc[i][3][rg] - mx);
                s += __shfl_xor(s, 1);
                s += __shfl_xor(s, 2);
                s += __shfl_xor(s, 4);
                s += __shfl_xor(s, 8);
                if (l15 == 0) redS[wn][wm * 64 + i * 16 + quad * 4 + rg] = s;
            }
        __syncthreads();
        if (tid < 128) {
            float nm = rowMn[tid];
            runL[tid] = runL[tid] * __expf(runM[tid] - nm) + redS[0][tid] + redS[1][tid];
            runM[tid] = nm;
        }
        // next gemm512's leading barrier protects LDS reuse
    }
    __syncthreads();
    if (tid < 128)
        statsP[((size_t)(b * 4 + nch)) * 4096 + mblk * 128 + tid] =
            make_float2(runM[tid], runL[tid]);
}

// combine the 4 n-chunk partials per row -> (max, 1/Z)
__global__ void reduce_stats(const float2* __restrict__ statsP,
                             float2* __restrict__ rowstats) {
    int t = blockIdx.x * 256 + threadIdx.x;  // 0..8191
    int b = t >> 12, m = t & 4095;
    float2 p[4];
    float M = -INFINITY;
#pragma unroll
    for (int ch = 0; ch < 4; ch++) {
        p[ch] = statsP[((size_t)(b * 4 + ch)) * 4096 + m];
        M = fmaxf(M, p[ch].x);
    }
    float L = 0.f;
#pragma unroll
    for (int ch = 0; ch < 4; ch++) L += p[ch].y * __expf(p[ch].x - M);
    rowstats[t] = make_float2(M, 1.0f / L);
}

// ---------------------------------------------------------------------------
// Pass 2: recompute scores, accumulate exp(s-max)/Z into column sums S.
// grid (nblk=32, mch=4, b=2); atomicAdd into S per column.
// ---------------------------------------------------------------------------
__global__ __launch_bounds__(256) void attn_pass2(
    const u16* __restrict__ Qb, const u16* __restrict__ Kb,
    const float2* __restrict__ rowstats, float* __restrict__ Sg) {
    __shared__ __align__(16) u16 As[128][40];
    __shared__ __align__(16) u16 Bs[128][40];
    __shared__ float2 rstat[128];
    __shared__ float colS[128];
    int tid = threadIdx.x;
    int nblk = blockIdx.x, mch = blockIdx.y, b = blockIdx.z;
    const u16* K = Kb + ((size_t)(b * 4096 + nblk * 128)) * 512;
    if (tid < 128) colS[tid] = 0.f;
    int lane = tid & 63, quad = lane >> 4, l15 = lane & 15;
    int wm = tid >> 7, wn = (tid >> 6) & 1;
    for (int mt = 0; mt < 8; mt++) {
        int m0 = mch * 1024 + mt * 128;
        const u16* Q = Qb + ((size_t)(b * 4096 + m0)) * 512;
        f32x4 acc[4][4];
#pragma unroll
        for (int i = 0; i < 4; i++)
#pragma unroll
            for (int j = 0; j < 4; j++) acc[i][j] = (f32x4){0.f, 0.f, 0.f, 0.f};
        gemm512(Q, K, As, Bs, acc, tid);
        if (tid < 128) rstat[tid] = rowstats[b * 4096 + m0 + tid];
        __syncthreads();
        float cp0 = 0.f, cp1 = 0.f, cp2 = 0.f, cp3 = 0.f;
#pragma unroll
        for (int i = 0; i < 4; i++)
#pragma unroll
            for (int rg = 0; rg < 4; rg++) {
                float2 st = rstat[wm * 64 + i * 16 + quad * 4 + rg];
                cp0 += __expf(acc[i][0][rg] - st.x) * st.y;
                cp1 += __expf(acc[i][1][rg] - st.x) * st.y;
                cp2 += __expf(acc[i][2][rg] - st.x) * st.y;
                cp3 += __expf(acc[i][3][rg] - st.x) * st.y;
            }
        cp0 += __shfl_xor(cp0, 16); cp0 += __shfl_xor(cp0, 32);
        cp1 += __shfl_xor(cp1, 16); cp1 += __shfl_xor(cp1, 32);
        cp2 += __shfl_xor(cp2, 16); cp2 += __shfl_xor(cp2, 32);
        cp3 += __shfl_xor(cp3, 16); cp3 += __shfl_xor(cp3, 32);
        if (lane < 16) {
            atomicAdd(&colS[wn * 64 + 0 * 16 + lane], cp0);
            atomicAdd(&colS[wn * 64 + 1 * 16 + lane], cp1);
            atomicAdd(&colS[wn * 64 + 2 * 16 + lane], cp2);
            atomicAdd(&colS[wn * 64 + 3 * 16 + lane], cp3);
        }
    }
    __syncthreads();
    if (tid < 128) atomicAdd(&Sg[b * 4096 + nblk * 128 + tid], colS[tid]);
}

// Vs = V * S/(1e-9+S) per row
__global__ void scale_v(const u16* __restrict__ Vb, const float* __restrict__ Sg,
                        u16* __restrict__ Vs) {
    int e = (blockIdx.x * 256 + threadIdx.x) * 4;
    int row = e >> 9;
    float s = Sg[row];
    float sc = s / (1e-9f + s);
    ushort4 v = *(const ushort4*)&Vb[e];
    ushort4 o;
    o.x = f2bf(bf2f(v.x) * sc);
    o.y = f2bf(bf2f(v.y) * sc);
    o.z = f2bf(bf2f(v.z) * sc);
    o.w = f2bf(bf2f(v.w) * sc);
    *(ushort4*)&Vs[e] = o;
}

// ---------------------------------------------------------------------------
// Final: out = relu(BN(Vs . Wo^T + bo)) + X  (fp32 out)
// ---------------------------------------------------------------------------
__global__ __launch_bounds__(256) void gemm_final(
    const u16* __restrict__ A, const u16* __restrict__ Bt,
    const float* __restrict__ bo, const float* __restrict__ g,
    const float* __restrict__ bb, const float* __restrict__ mean,
    const float* __restrict__ var, const float* __restrict__ X,
    float* __restrict__ out) {
    __shared__ __align__(16) u16 As[128][40];
    __shared__ __align__(16) u16 Bs[128][40];
    int tid = threadIdx.x;
    int m0 = blockIdx.x * 128, n0 = blockIdx.y * 128;
    f32x4 acc[4][4];
#pragma unroll
    for (int i = 0; i < 4; i++)
#pragma unroll
        for (int j = 0; j < 4; j++) acc[i][j] = (f32x4){0.f, 0.f, 0.f, 0.f};
    gemm512(A + (size_t)m0 * 512, Bt + (size_t)n0 * 512, As, Bs, acc, tid);
    int lane = tid & 63, quad = lane >> 4, l15 = lane & 15;
    int wm = tid >> 7, wn = (tid >> 6) & 1;
#pragma unroll
    for (int j = 0; j < 4; j++) {
        int n = n0 + wn * 64 + j * 16 + l15;
        float aj = rsqrtf(var[n] + 1e-5f) * g[n];
        float cj = bb[n] - mean[n] * aj;
        float bj = bo[n];
#pragma unroll
        for (int i = 0; i < 4; i++)
#pragma unroll
            for (int rg = 0; rg < 4; rg++) {
                int m = m0 + wm * 64 + i * 16 + quad * 4 + rg;
                float x = acc[i][j][rg] + bj;
                float y = x * aj + cj;
                float z = fmaxf(y, 0.f) + X[(size_t)m * 512 + n];
                out[(size_t)m * 512 + n] = z;
            }
    }
}

// ---------------------------------------------------------------------------
extern "C" void kernel_launch(void* const* d_in, const int* in_sizes, int n_in,
                              void* d_out, int out_size, void* d_ws, size_t ws_size,
                              hipStream_t stream) {
    const float* X  = (const float*)d_in[0];
    const float* Wq = (const float*)d_in[1];
    const float* Wk = (const float*)d_in[2];
    const float* Wv = (const float*)d_in[3];
    const float* Wo = (const float*)d_in[4];
    const float* bq = (const float*)d_in[5];
    const float* bk = (const float*)d_in[6];
    const float* bv = (const float*)d_in[7];
    const float* bo = (const float*)d_in[8];
    const float* g    = (const float*)d_in[9];
    const float* bb   = (const float*)d_in[10];
    const float* mean = (const float*)d_in[11];
    const float* var  = (const float*)d_in[12];
    float* out = (float*)d_out;

    char* ws = (char*)d_ws;
    u16* Xb  = (u16*)(ws + 0);                  // 8 MB
    u16* Wqt = (u16*)(ws + 8388608);
    u16* Wkt = (u16*)(ws + 8912896);
    u16* Wvt = (u16*)(ws + 9437184);
    u16* Wot = (u16*)(ws + 9961472);
    u16* Qb  = (u16*)(ws + 10485760);
    u16* Kb  = (u16*)(ws + 18874368);
    u16* Vb  = (u16*)(ws + 27262976);
    u16* Vs  = (u16*)(ws + 35651584);
    float2* statsP   = (float2*)(ws + 44040192);  // [B][4][4096]
    float2* rowstats = (float2*)(ws + 44302336);  // [B][4096] (max, 1/Z)
    float* Sg        = (float*)(ws + 44367872);   // [B][4096]

    convert_x<<<4096, 256, 0, stream>>>(X, Xb);
    transpose_w<<<dim3(16, 16, 4), dim3(32, 8), 0, stream>>>(
        Wq, Wk, Wv, Wo, Wqt, Wkt, Wvt, Wot);
    gemm_bias_bf16<<<dim3(64, 4), 256, 0, stream>>>(Xb, Wqt, bq, Qb);
    gemm_bias_bf16<<<dim3(64, 4), 256, 0, stream>>>(Xb, Wkt, bk, Kb);
    gemm_bias_bf16<<<dim3(64, 4), 256, 0, stream>>>(Xb, Wvt, bv, Vb);
    attn_pass1<<<dim3(32, 4, 2), 256, 0, stream>>>(Qb, Kb, statsP);
    reduce_stats<<<32, 256, 0, stream>>>(statsP, rowstats);
    hipMemsetAsync(Sg, 0, 2 * 4096 * sizeof(float), stream);
    attn_pass2<<<dim3(32, 4, 2), 256, 0, stream>>>(Qb, Kb, rowstats, Sg);
    scale_v<<<4096, 256, 0, stream>>>(Vb, Sg, Vs);
    gemm_final<<<dim3(64, 4), 256, 0, stream>>>(Vs, Wot, bo, g, bb, mean, var, X, out);
}

// Round 2
// 265.074 us; speedup vs baseline: 1.4329x; 1.4329x over previous
//
#include <hip/hip_runtime.h>
#include <hip/hip_bf16.h>

typedef unsigned short u16;
typedef __attribute__((ext_vector_type(8))) short short8;
typedef __attribute__((ext_vector_type(4))) float f32x4;

__device__ __forceinline__ u16 f2bf(float f) {
    union { float f; unsigned u; } v; v.f = f;
    unsigned r = v.u + 0x7fffu + ((v.u >> 16) & 1u);
    return (u16)(r >> 16);
}
__device__ __forceinline__ float bf2f(u16 h) {
    union { unsigned u; float f; } v; v.u = ((unsigned)h) << 16;
    return v.f;
}

// async 16B global->LDS DMA (m97 pattern). lds base must be wave-uniform;
// each lane deposits at base + lane*16.
__device__ __forceinline__ void async_cp16(const u16* g, u16* l) {
    __builtin_amdgcn_global_load_lds(
        (const __attribute__((address_space(1))) void*)g,
        (__attribute__((address_space(3))) void*)l, 16, 0, 0);
}

// ---------------------------------------------------------------------------
// Shared 128x128x512 MFMA core: A [128,512] bf16 row-major, B^T [128,512] bf16
// row-major (computes A . B^T). 4 waves, each 64x64 (4x4 tiles of 16x16x32).
// LDS tiles UNPADDED [128][32] (64B rows) — required by global_load_lds's
// contiguous lane-order deposit. Staging: 2 DMA instrs/wave/tile.
// ---------------------------------------------------------------------------
__device__ __forceinline__ void gemm512(const u16* __restrict__ A,
                                        const u16* __restrict__ B,
                                        u16* As, u16* Bs,
                                        f32x4 acc[4][4], int tid) {
    const int lane = tid & 63, w = tid >> 6;
    const int quad = lane >> 4, l15 = lane & 15;
    const int wm = tid >> 7, wn = (tid >> 6) & 1;
    // staging geometry: instr t in {0,1}: rows w*32 + t*16 + lane/4,
    // col elems (lane&3)*8; LDS base = tile + (w*2+t)*512 elems.
    const int srow0 = w * 32 + (lane >> 2);
    const int srow1 = srow0 + 16;
    const int scol = (lane & 3) * 8;
    u16* la0 = As + (w * 2 + 0) * 512;
    u16* la1 = As + (w * 2 + 1) * 512;
    u16* lb0 = Bs + (w * 2 + 0) * 512;
    u16* lb1 = Bs + (w * 2 + 1) * 512;
    for (int k0 = 0; k0 < 512; k0 += 32) {
        __syncthreads();
        async_cp16(A + (size_t)srow0 * 512 + k0 + scol, la0);
        async_cp16(A + (size_t)srow1 * 512 + k0 + scol, la1);
        async_cp16(B + (size_t)srow0 * 512 + k0 + scol, lb0);
        async_cp16(B + (size_t)srow1 * 512 + k0 + scol, lb1);
        __syncthreads();  // drains vmcnt before any lane reads LDS
        short8 af[4], bfr[4];
#pragma unroll
        for (int i = 0; i < 4; i++)
            af[i] = *(const short8*)&As[(wm * 64 + i * 16 + l15) * 32 + quad * 8];
#pragma unroll
        for (int j = 0; j < 4; j++)
            bfr[j] = *(const short8*)&Bs[(wn * 64 + j * 16 + l15) * 32 + quad * 8];
#pragma unroll
        for (int i = 0; i < 4; i++)
#pragma unroll
            for (int j = 0; j < 4; j++)
                acc[i][j] = __builtin_amdgcn_mfma_f32_16x16x32_bf16(
                    af[i], bfr[j], acc[i][j], 0, 0, 0);
    }
}

// ---------------------------------------------------------------------------
// Prep kernels
// ---------------------------------------------------------------------------
__global__ void convert_x(const float* __restrict__ X, u16* __restrict__ Xb) {
    int idx = (blockIdx.x * 256 + threadIdx.x) * 4;
    float4 v = *(const float4*)&X[idx];
    ushort4 o;
    o.x = f2bf(v.x); o.y = f2bf(v.y); o.z = f2bf(v.z); o.w = f2bf(v.w);
    *(ushort4*)&Xb[idx] = o;
}

__global__ void transpose_w(const float* __restrict__ W0, const float* __restrict__ W1,
                            const float* __restrict__ W2, const float* __restrict__ W3,
                            u16* __restrict__ T0, u16* __restrict__ T1,
                            u16* __restrict__ T2, u16* __restrict__ T3) {
    const float* src; u16* dst;
    switch (blockIdx.z) {
        case 0: src = W0; dst = T0; break;
        case 1: src = W1; dst = T1; break;
        case 2: src = W2; dst = T2; break;
        default: src = W3; dst = T3; break;
    }
    __shared__ float tile[32][33];
    int bo_ = blockIdx.x * 32;  // output-channel offset
    int bi  = blockIdx.y * 32;  // input-channel offset
#pragma unroll
    for (int t = 0; t < 4; t++) {
        int i = bi + threadIdx.y + t * 8;
        tile[threadIdx.y + t * 8][threadIdx.x] = src[i * 512 + bo_ + threadIdx.x];
    }
    __syncthreads();
#pragma unroll
    for (int t = 0; t < 4; t++) {
        int o = bo_ + threadIdx.y + t * 8;
        dst[o * 512 + bi + threadIdx.x] = f2bf(tile[threadIdx.x][threadIdx.y + t * 8]);
    }
}

// ---------------------------------------------------------------------------
// Fused QKV projection: z selects {Wq,bq,Q} / {Wk,bk,K} / {Wv,bv,V}.
// grid (64 mblk, 4 nblk, 3)
// ---------------------------------------------------------------------------
__global__ __launch_bounds__(256) void gemm_qkv(
    const u16* __restrict__ Xb, const u16* __restrict__ Wall,
    const float* __restrict__ bq, const float* __restrict__ bk,
    const float* __restrict__ bv, u16* __restrict__ Qall) {
    __shared__ __align__(16) u16 As[128 * 32];
    __shared__ __align__(16) u16 Bs[128 * 32];
    int tid = threadIdx.x;
    int m0 = blockIdx.x * 128, n0 = blockIdx.y * 128, z = blockIdx.z;
    const u16* Bt = Wall + (size_t)z * 262144 + (size_t)n0 * 512;
    const float* bias = (z == 0) ? bq : (z == 1) ? bk : bv;
    u16* C = Qall + (size_t)z * 4194304;
    f32x4 acc[4][4];
#pragma unroll
    for (int i = 0; i < 4; i++)
#pragma unroll
        for (int j = 0; j < 4; j++) acc[i][j] = (f32x4){0.f, 0.f, 0.f, 0.f};
    gemm512(Xb + (size_t)m0 * 512, Bt, As, Bs, acc, tid);
    int lane = tid & 63, quad = lane >> 4, l15 = lane & 15;
    int wm = tid >> 7, wn = (tid >> 6) & 1;
#pragma unroll
    for (int j = 0; j < 4; j++) {
        int n = n0 + wn * 64 + j * 16 + l15;
        float bvv = bias[n];
#pragma unroll
        for (int i = 0; i < 4; i++)
#pragma unroll
            for (int rg = 0; rg < 4; rg++) {
                int m = m0 + wm * 64 + i * 16 + quad * 4 + rg;
                C[(size_t)m * 512 + n] = f2bf(acc[i][j][rg] + bvv);
            }
    }
}

// ---------------------------------------------------------------------------
// Pass 1: per-row running max / sum-exp over an n-chunk of 512 cols.
// grid (mblk=32, nch=8, b=2) -> 512 blocks, 2 blocks/CU
// ---------------------------------------------------------------------------
__global__ __launch_bounds__(256) void attn_pass1(
    const u16* __restrict__ Qb, const u16* __restrict__ Kb,
    float2* __restrict__ statsP) {
    __shared__ __align__(16) u16 As[128 * 32];
    __shared__ __align__(16) u16 Bs[128 * 32];
    __shared__ float redM[2][128], redS[2][128], rowMn[128], runM[128], runL[128];
    int tid = threadIdx.x;
    int mblk = blockIdx.x, nch = blockIdx.y, b = blockIdx.z;
    const u16* Q = Qb + ((size_t)(b * 4096 + mblk * 128)) * 512;
    if (tid < 128) { runM[tid] = -INFINITY; runL[tid] = 0.f; }
    int lane = tid & 63, quad = lane >> 4, l15 = lane & 15;
    int wm = tid >> 7, wn = (tid >> 6) & 1;
    for (int nt = 0; nt < 4; nt++) {
        const u16* K = Kb + ((size_t)(b * 4096 + nch * 512 + nt * 128)) * 512;
        f32x4 acc[4][4];
#pragma unroll
        for (int i = 0; i < 4; i++)
#pragma unroll
            for (int j = 0; j < 4; j++) acc[i][j] = (f32x4){0.f, 0.f, 0.f, 0.f};
        gemm512(Q, K, As, Bs, acc, tid);  // leading internal barrier covers init
#pragma unroll
        for (int i = 0; i < 4; i++)
#pragma unroll
            for (int rg = 0; rg < 4; rg++) {
                float v = fmaxf(fmaxf(acc[i][0][rg], acc[i][1][rg]),
                                fmaxf(acc[i][2][rg], acc[i][3][rg]));
                v = fmaxf(v, __shfl_xor(v, 1));
                v = fmaxf(v, __shfl_xor(v, 2));
                v = fmaxf(v, __shfl_xor(v, 4));
                v = fmaxf(v, __shfl_xor(v, 8));
                if (l15 == 0) redM[wn][wm * 64 + i * 16 + quad * 4 + rg] = v;
            }
        __syncthreads();
        if (tid < 128)
            rowMn[tid] = fmaxf(runM[tid], fmaxf(redM[0][tid], redM[1][tid]));
        __syncthreads();
#pragma unroll
        for (int i = 0; i < 4; i++)
#pragma unroll
            for (int rg = 0; rg < 4; rg++) {
                float mx = rowMn[wm * 64 + i * 16 + quad * 4 + rg];
                float s = __expf(acc[i][0][rg] - mx) + __expf(acc[i][1][rg] - mx) +
                          __expf(acc[i][2][rg] - mx) + __expf(acc[i][3][rg] - mx);
                s += __shfl_xor(s, 1);
                s += __shfl_xor(s, 2);
                s += __shfl_xor(s, 4);
                s += __shfl_xor(s, 8);
                if (l15 == 0) redS[wn][wm * 64 + i * 16 + quad * 4 + rg] = s;
            }
        __syncthreads();
        if (tid < 128) {
            float nm = rowMn[tid];
            runL[tid] = runL[tid] * __expf(runM[tid] - nm) + redS[0][tid] + redS[1][tid];
            runM[tid] = nm;
        }
        // next gemm512's leading barrier protects LDS + runM/runL reuse
    }
    __syncthreads();
    if (tid < 128)
        statsP[((size_t)(b * 8 + nch)) * 4096 + mblk * 128 + tid] =
            make_float2(runM[tid], runL[tid]);
}

// combine the 8 n-chunk partials per row -> (max, 1/Z)
__global__ void reduce_stats(const float2* __restrict__ statsP,
                             float2* __restrict__ rowstats) {
    int t = blockIdx.x * 256 + threadIdx.x;  // 0..8191
    int b = t >> 12, m = t & 4095;
    float M = -INFINITY;
    float2 p[8];
#pragma unroll
    for (int ch = 0; ch < 8; ch++) {
        p[ch] = statsP[((size_t)(b * 8 + ch)) * 4096 + m];
        M = fmaxf(M, p[ch].x);
    }
    float L = 0.f;
#pragma unroll
    for (int ch = 0; ch < 8; ch++) L += p[ch].y * __expf(p[ch].x - M);
    rowstats[t] = make_float2(M, 1.0f / L);
}

// ---------------------------------------------------------------------------
// Pass 2: recompute scores, accumulate exp(s-max)/Z into column sums S.
// grid (nblk=32, mch=8, b=2) -> 512 blocks; atomicAdd into S per column.
// ---------------------------------------------------------------------------
__global__ __launch_bounds__(256) void attn_pass2(
    const u16* __restrict__ Qb, const u16* __restrict__ Kb,
    const float2* __restrict__ rowstats, float* __restrict__ Sg) {
    __shared__ __align__(16) u16 As[128 * 32];
    __shared__ __align__(16) u16 Bs[128 * 32];
    __shared__ float2 rstat[128];
    __shared__ float colS[128];
    int tid = threadIdx.x;
    int nblk = blockIdx.x, mch = blockIdx.y, b = blockIdx.z;
    const u16* K = Kb + ((size_t)(b * 4096 + nblk * 128)) * 512;
    if (tid < 128) colS[tid] = 0.f;
    int lane = tid & 63, quad = lane >> 4, l15 = lane & 15;
    int wm = tid >> 7, wn = (tid >> 6) & 1;
    for (int mt = 0; mt < 4; mt++) {
        int m0 = mch * 512 + mt * 128;
        const u16* Q = Qb + ((size_t)(b * 4096 + m0)) * 512;
        f32x4 acc[4][4];
#pragma unroll
        for (int i = 0; i < 4; i++)
#pragma unroll
            for (int j = 0; j < 4; j++) acc[i][j] = (f32x4){0.f, 0.f, 0.f, 0.f};
        gemm512(Q, K, As, Bs, acc, tid);
        if (tid < 128) rstat[tid] = rowstats[b * 4096 + m0 + tid];
        __syncthreads();
        float cp0 = 0.f, cp1 = 0.f, cp2 = 0.f, cp3 = 0.f;
#pragma unroll
        for (int i = 0; i < 4; i++)
#pragma unroll
            for (int rg = 0; rg < 4; rg++) {
                float2 st = rstat[wm * 64 + i * 16 + quad * 4 + rg];
                cp0 += __expf(acc[i][0][rg] - st.x) * st.y;
                cp1 += __expf(acc[i][1][rg] - st.x) * st.y;
                cp2 += __expf(acc[i][2][rg] - st.x) * st.y;
                cp3 += __expf(acc[i][3][rg] - st.x) * st.y;
            }
        cp0 += __shfl_xor(cp0, 16); cp0 += __shfl_xor(cp0, 32);
        cp1 += __shfl_xor(cp1, 16); cp1 += __shfl_xor(cp1, 32);
        cp2 += __shfl_xor(cp2, 16); cp2 += __shfl_xor(cp2, 32);
        cp3 += __shfl_xor(cp3, 16); cp3 += __shfl_xor(cp3, 32);
        if (lane < 16) {
            atomicAdd(&colS[wn * 64 + 0 * 16 + lane], cp0);
            atomicAdd(&colS[wn * 64 + 1 * 16 + lane], cp1);
            atomicAdd(&colS[wn * 64 + 2 * 16 + lane], cp2);
            atomicAdd(&colS[wn * 64 + 3 * 16 + lane], cp3);
        }
        __syncthreads();  // colS visible before next iter's accumulation reuses it
    }
    if (tid < 128) atomicAdd(&Sg[b * 4096 + nblk * 128 + tid], colS[tid]);
}

// Vs = V * S/(1e-9+S) per row
__global__ void scale_v(const u16* __restrict__ Vb, const float* __restrict__ Sg,
                        u16* __restrict__ Vs) {
    int e = (blockIdx.x * 256 + threadIdx.x) * 4;
    int row = e >> 9;
    float s = Sg[row];
    float sc = s / (1e-9f + s);
    ushort4 v = *(const ushort4*)&Vb[e];
    ushort4 o;
    o.x = f2bf(bf2f(v.x) * sc);
    o.y = f2bf(bf2f(v.y) * sc);
    o.z = f2bf(bf2f(v.z) * sc);
    o.w = f2bf(bf2f(v.w) * sc);
    *(ushort4*)&Vs[e] = o;
}

// ---------------------------------------------------------------------------
// Final: out = relu(BN(Vs . Wo^T + bo)) + X  (fp32 out)
// ---------------------------------------------------------------------------
__global__ __launch_bounds__(256) void gemm_final(
    const u16* __restrict__ A, const u16* __restrict__ Bt,
    const float* __restrict__ bo, const float* __restrict__ g,
    const float* __restrict__ bb, const float* __restrict__ mean,
    const float* __restrict__ var, const float* __restrict__ X,
    float* __restrict__ out) {
    __shared__ __align__(16) u16 As[128 * 32];
    __shared__ __align__(16) u16 Bs[128 * 32];
    int tid = threadIdx.x;
    int m0 = blockIdx.x * 128, n0 = blockIdx.y * 128;
    f32x4 acc[4][4];
#pragma unroll
    for (int i = 0; i < 4; i++)
#pragma unroll
        for (int j = 0; j < 4; j++) acc[i][j] = (f32x4){0.f, 0.f, 0.f, 0.f};
    gemm512(A + (size_t)m0 * 512, Bt + (size_t)n0 * 512, As, Bs, acc, tid);
    int lane = tid & 63, quad = lane >> 4, l15 = lane & 15;
    int wm = tid >> 7, wn = (tid >> 6) & 1;
#pragma unroll
    for (int j = 0; j < 4; j++) {
        int n = n0 + wn * 64 + j * 16 + l15;
        float aj = rsqrtf(var[n] + 1e-5f) * g[n];
        float cj = bb[n] - mean[n] * aj;
        float bj = bo[n];
#pragma unroll
        for (int i = 0; i < 4; i++)
#pragma unroll
            for (int rg = 0; rg < 4; rg++) {
                int m = m0 + wm * 64 + i * 16 + quad * 4 + rg;
                float x = acc[i][j][rg] + bj;
                float y = x * aj + cj;
                float z = fmaxf(y, 0.f) + X[(size_t)m * 512 + n];
                out[(size_t)m * 512 + n] = z;
            }
    }
}

// ---------------------------------------------------------------------------
extern "C" void kernel_launch(void* const* d_in, const int* in_sizes, int n_in,
                              void* d_out, int out_size, void* d_ws, size_t ws_size,
                              hipStream_t stream) {
    const float* X  = (const float*)d_in[0];
    const float* Wq = (const float*)d_in[1];
    const float* Wk = (const float*)d_in[2];
    const float* Wv = (const float*)d_in[3];
    const float* Wo = (const float*)d_in[4];
    const float* bq = (const float*)d_in[5];
    const float* bk = (const float*)d_in[6];
    const float* bv = (const float*)d_in[7];
    const float* bo = (const float*)d_in[8];
    const float* g    = (const float*)d_in[9];
    const float* bb   = (const float*)d_in[10];
    const float* mean = (const float*)d_in[11];
    const float* var  = (const float*)d_in[12];
    float* out = (float*)d_out;

    char* ws = (char*)d_ws;
    u16* Xb  = (u16*)(ws + 0);                    // 8 MB
    u16* Wqt = (u16*)(ws + 8388608);              // 3x512KB contiguous (Wq,Wk,Wv)
    u16* Wkt = (u16*)(ws + 8912896);
    u16* Wvt = (u16*)(ws + 9437184);
    u16* Wot = (u16*)(ws + 9961472);
    u16* Qb  = (u16*)(ws + 10485760);             // Q,K,V contiguous 3x8MB
    u16* Kb  = (u16*)(ws + 18874368);
    u16* Vb  = (u16*)(ws + 27262976);
    u16* Vs  = (u16*)(ws + 35651584);
    float2* statsP   = (float2*)(ws + 44040192);  // [B][8][4096] = 512 KB
    float2* rowstats = (float2*)(ws + 44564480);  // [B][4096] (max, 1/Z)
    float* Sg        = (float*)(ws + 44630016);   // [B][4096]

    convert_x<<<4096, 256, 0, stream>>>(X, Xb);
    transpose_w<<<dim3(16, 16, 4), dim3(32, 8), 0, stream>>>(
        Wq, Wk, Wv, Wo, Wqt, Wkt, Wvt, Wot);
    gemm_qkv<<<dim3(64, 4, 3), 256, 0, stream>>>(Xb, Wqt, bq, bk, bv, Qb);
    attn_pass1<<<dim3(32, 8, 2), 256, 0, stream>>>(Qb, Kb, statsP);
    reduce_stats<<<32, 256, 0, stream>>>(statsP, rowstats);
    hipMemsetAsync(Sg, 0, 2 * 4096 * sizeof(float), stream);
    attn_pass2<<<dim3(32, 8, 2), 256, 0, stream>>>(Qb, Kb, rowstats, Sg);
    scale_v<<<4096, 256, 0, stream>>>(Vb, Sg, Vs);
    gemm_final<<<dim3(64, 4), 256, 0, stream>>>(Vs, Wot, bo, g, bb, mean, var, X, out);
}

// Round 4
// 235.036 us; speedup vs baseline: 1.6160x; 1.1278x over previous
//
#include <hip/hip_runtime.h>
#include <hip/hip_bf16.h>

typedef unsigned short u16;
typedef __attribute__((ext_vector_type(8))) short short8;
typedef __attribute__((ext_vector_type(4))) float f32x4;

__device__ __forceinline__ u16 f2bf(float f) {
    union { float f; unsigned u; } v; v.f = f;
    unsigned r = v.u + 0x7fffu + ((v.u >> 16) & 1u);
    return (u16)(r >> 16);
}

__device__ __forceinline__ float fexp2(float x) {
#if __has_builtin(__builtin_amdgcn_exp2f)
    return __builtin_amdgcn_exp2f(x);
#else
    return __expf(x * 0.6931471805599453f);
#endif
}

// async 16B global->LDS DMA (m97 pattern). lds base must be wave-uniform;
// each lane deposits at base + lane*16.
__device__ __forceinline__ void async_cp16(const u16* g, u16* l) {
    __builtin_amdgcn_global_load_lds(
        (const __attribute__((address_space(1))) void*)g,
        (__attribute__((address_space(3))) void*)l, 16, 0, 0);
}

// ---------------------------------------------------------------------------
// Shared 128x128x512 MFMA core: A [128,512] bf16 row-major, B^T [128,512] bf16
// row-major (computes A . B^T). 4 waves, each 64x64 (4x4 tiles of 16x16x32).
// LDS tiles UNPADDED [128][32] — required by global_load_lds deposit order.
// ---------------------------------------------------------------------------
__device__ __forceinline__ void gemm512(const u16* __restrict__ A,
                                        const u16* __restrict__ B,
                                        u16* As, u16* Bs,
                                        f32x4 acc[4][4], int tid) {
    const int lane = tid & 63, w = tid >> 6;
    const int quad = lane >> 4, l15 = lane & 15;
    const int wm = tid >> 7, wn = (tid >> 6) & 1;
    const int srow0 = w * 32 + (lane >> 2);
    const int srow1 = srow0 + 16;
    const int scol = (lane & 3) * 8;
    u16* la0 = As + (w * 2 + 0) * 512;
    u16* la1 = As + (w * 2 + 1) * 512;
    u16* lb0 = Bs + (w * 2 + 0) * 512;
    u16* lb1 = Bs + (w * 2 + 1) * 512;
    for (int k0 = 0; k0 < 512; k0 += 32) {
        __syncthreads();
        async_cp16(A + (size_t)srow0 * 512 + k0 + scol, la0);
        async_cp16(A + (size_t)srow1 * 512 + k0 + scol, la1);
        async_cp16(B + (size_t)srow0 * 512 + k0 + scol, lb0);
        async_cp16(B + (size_t)srow1 * 512 + k0 + scol, lb1);
        __syncthreads();
        short8 af[4], bfr[4];
#pragma unroll
        for (int i = 0; i < 4; i++)
            af[i] = *(const short8*)&As[(wm * 64 + i * 16 + l15) * 32 + quad * 8];
#pragma unroll
        for (int j = 0; j < 4; j++)
            bfr[j] = *(const short8*)&Bs[(wn * 64 + j * 16 + l15) * 32 + quad * 8];
#pragma unroll
        for (int i = 0; i < 4; i++)
#pragma unroll
            for (int j = 0; j < 4; j++)
                acc[i][j] = __builtin_amdgcn_mfma_f32_16x16x32_bf16(
                    af[i], bfr[j], acc[i][j], 0, 0, 0);
    }
}

// ---------------------------------------------------------------------------
// Prep kernels
// ---------------------------------------------------------------------------
__global__ void convert_x(const float* __restrict__ X, u16* __restrict__ Xb) {
    int idx = (blockIdx.x * 256 + threadIdx.x) * 4;
    float4 v = *(const float4*)&X[idx];
    ushort4 o;
    o.x = f2bf(v.x); o.y = f2bf(v.y); o.z = f2bf(v.z); o.w = f2bf(v.w);
    *(ushort4*)&Xb[idx] = o;
}

__global__ void transpose_w(const float* __restrict__ W0, const float* __restrict__ W1,
                            const float* __restrict__ W2, const float* __restrict__ W3,
                            u16* __restrict__ T0, u16* __restrict__ T1,
                            u16* __restrict__ T2, u16* __restrict__ T3) {
    const float* src; u16* dst;
    switch (blockIdx.z) {
        case 0: src = W0; dst = T0; break;
        case 1: src = W1; dst = T1; break;
        case 2: src = W2; dst = T2; break;
        default: src = W3; dst = T3; break;
    }
    __shared__ float tile[32][33];
    int bo_ = blockIdx.x * 32;
    int bi  = blockIdx.y * 32;
#pragma unroll
    for (int t = 0; t < 4; t++) {
        int i = bi + threadIdx.y + t * 8;
        tile[threadIdx.y + t * 8][threadIdx.x] = src[i * 512 + bo_ + threadIdx.x];
    }
    __syncthreads();
#pragma unroll
    for (int t = 0; t < 4; t++) {
        int o = bo_ + threadIdx.y + t * 8;
        dst[o * 512 + bi + threadIdx.x] = f2bf(tile[threadIdx.x][threadIdx.y + t * 8]);
    }
}

// ---------------------------------------------------------------------------
// Fused QKV projection. z==0 (Q) additionally scaled by log2(e) so the
// score GEMMs come out in base-2 domain (exp2 instead of exp).
// ---------------------------------------------------------------------------
__global__ __launch_bounds__(256) void gemm_qkv(
    const u16* __restrict__ Xb, const u16* __restrict__ Wall,
    const float* __restrict__ bq, const float* __restrict__ bk,
    const float* __restrict__ bv, u16* __restrict__ Qall) {
    __shared__ __align__(16) u16 As[128 * 32];
    __shared__ __align__(16) u16 Bs[128 * 32];
    int tid = threadIdx.x;
    int m0 = blockIdx.x * 128, n0 = blockIdx.y * 128, z = blockIdx.z;
    const u16* Bt = Wall + (size_t)z * 262144 + (size_t)n0 * 512;
    const float* bias = (z == 0) ? bq : (z == 1) ? bk : bv;
    const float qs = (z == 0) ? 1.44269504088896340736f : 1.0f;
    u16* C = Qall + (size_t)z * 4194304;
    f32x4 acc[4][4];
#pragma unroll
    for (int i = 0; i < 4; i++)
#pragma unroll
        for (int j = 0; j < 4; j++) acc[i][j] = (f32x4){0.f, 0.f, 0.f, 0.f};
    gemm512(Xb + (size_t)m0 * 512, Bt, As, Bs, acc, tid);
    int lane = tid & 63, quad = lane >> 4, l15 = lane & 15;
    int wm = tid >> 7, wn = (tid >> 6) & 1;
#pragma unroll
    for (int j = 0; j < 4; j++) {
        int n = n0 + wn * 64 + j * 16 + l15;
        float bvv = bias[n];
#pragma unroll
        for (int i = 0; i < 4; i++)
#pragma unroll
            for (int rg = 0; rg < 4; rg++) {
                int m = m0 + wm * 64 + i * 16 + quad * 4 + rg;
                C[(size_t)m * 512 + n] = f2bf((acc[i][j][rg] + bvv) * qs);
            }
    }
}

// ---------------------------------------------------------------------------
// Pass 1: per-row (max, sum 2^x) over an n-chunk of 512 cols.
// Per-thread online state in registers. Skip threshold -30 is safe HERE:
// a skipped group cannot contain the max (vm <= M-30), so M stays exact and
// Z only loses <= 4096*2^-30 relative — invisible through c = M+log2(Z).
// grid (32, 8, 2).
// ---------------------------------------------------------------------------
__global__ __launch_bounds__(256) void attn_pass1(
    const u16* __restrict__ Qb, const u16* __restrict__ Kb,
    float2* __restrict__ statsP) {
    __shared__ __align__(16) u16 As[128 * 32];
    __shared__ __align__(16) u16 Bs[128 * 32];
    int tid = threadIdx.x;
    int mblk = blockIdx.x, nch = blockIdx.y, b = blockIdx.z;
    const u16* Q = Qb + ((size_t)(b * 4096 + mblk * 128)) * 512;
    int lane = tid & 63, quad = lane >> 4, l15 = lane & 15;
    int wm = tid >> 7, wn = (tid >> 6) & 1;
    float runM[4][4], runL[4][4];
#pragma unroll
    for (int i = 0; i < 4; i++)
#pragma unroll
        for (int rg = 0; rg < 4; rg++) { runM[i][rg] = -INFINITY; runL[i][rg] = 0.f; }
    for (int nt = 0; nt < 4; nt++) {
        const u16* K = Kb + ((size_t)(b * 4096 + nch * 512 + nt * 128)) * 512;
        f32x4 acc[4][4];
#pragma unroll
        for (int i = 0; i < 4; i++)
#pragma unroll
            for (int j = 0; j < 4; j++) acc[i][j] = (f32x4){0.f, 0.f, 0.f, 0.f};
        gemm512(Q, K, As, Bs, acc, tid);
#pragma unroll
        for (int i = 0; i < 4; i++)
#pragma unroll
            for (int rg = 0; rg < 4; rg++) {
                float v0 = acc[i][0][rg], v1 = acc[i][1][rg];
                float v2 = acc[i][2][rg], v3 = acc[i][3][rg];
                float vm = fmaxf(fmaxf(v0, v1), fmaxf(v2, v3));
                float mo = runM[i][rg];
                if (vm > mo - 30.f) {  // else: Z-mass <4*2^-30 rel., M unchanged
                    float nm = fmaxf(mo, vm);
                    runL[i][rg] = runL[i][rg] * fexp2(mo - nm) +
                                  fexp2(v0 - nm) + fexp2(v1 - nm) +
                                  fexp2(v2 - nm) + fexp2(v3 - nm);
                    runM[i][rg] = nm;
                }
            }
    }
    // combine across the 16 l15 lanes (same row, different cols)
#pragma unroll
    for (int i = 0; i < 4; i++)
#pragma unroll
        for (int rg = 0; rg < 4; rg++) {
            float M = runM[i][rg], L = runL[i][rg];
#pragma unroll
            for (int d = 1; d < 16; d <<= 1) {
                float Mo = __shfl_xor(M, d);
                float Lo = __shfl_xor(L, d);
                float Mn = fmaxf(M, Mo);
                L = L * fexp2(M - Mn) + Lo * fexp2(Mo - Mn);
                M = Mn;
            }
            if (l15 == 0)
                statsP[((size_t)(b * 16 + nch * 2 + wn)) * 4096 +
                       mblk * 128 + wm * 64 + i * 16 + quad * 4 + rg] =
                    make_float2(M, L);
        }
}

// combine the 16 partials per row -> c = M + log2(Z)
__global__ void reduce_stats(const float2* __restrict__ statsP,
                             float* __restrict__ cstat) {
    int t = blockIdx.x * 256 + threadIdx.x;  // 0..8191
    int b = t >> 12, m = t & 4095;
    float2 p[16];
    float M = -INFINITY;
#pragma unroll
    for (int ch = 0; ch < 16; ch++) {
        p[ch] = statsP[((size_t)(b * 16 + ch)) * 4096 + m];
        M = fmaxf(M, p[ch].x);
    }
    float L = 0.f;
#pragma unroll
    for (int ch = 0; ch < 16; ch++) L += p[ch].y * fexp2(p[ch].x - M);
    cstat[t] = M + __log2f(L);
}

// ---------------------------------------------------------------------------
// Pass 2: recompute scores, accumulate 2^(s-c) into column sums S.
// Column partials live in registers across the whole mt loop.
// SKIP THRESHOLD -60, NOT -30: downstream is scale=S/(1e-9+S), sensitive
// exactly at S~2^-30. Dropped mass must be << 1e-9: 4096*2^-60 = 2^-48,
// worst-case scale error 3.6e-6. (-30 caused absmax 0.71 in round 3.)
// grid (32, 8, 2).
// ---------------------------------------------------------------------------
__global__ __launch_bounds__(256) void attn_pass2(
    const u16* __restrict__ Qb, const u16* __restrict__ Kb,
    const float* __restrict__ cstat, float* __restrict__ Sg) {
    __shared__ __align__(16) u16 As[128 * 32];
    __shared__ __align__(16) u16 Bs[128 * 32];
    int tid = threadIdx.x;
    int nblk = blockIdx.x, mch = blockIdx.y, b = blockIdx.z;
    const u16* K = Kb + ((size_t)(b * 4096 + nblk * 128)) * 512;
    int lane = tid & 63, quad = lane >> 4, l15 = lane & 15;
    int wm = tid >> 7, wn = (tid >> 6) & 1;
    float cp0 = 0.f, cp1 = 0.f, cp2 = 0.f, cp3 = 0.f;
    for (int mt = 0; mt < 4; mt++) {
        int m0 = mch * 512 + mt * 128;
        const u16* Q = Qb + ((size_t)(b * 4096 + m0)) * 512;
        f32x4 acc[4][4];
#pragma unroll
        for (int i = 0; i < 4; i++)
#pragma unroll
            for (int j = 0; j < 4; j++) acc[i][j] = (f32x4){0.f, 0.f, 0.f, 0.f};
        gemm512(Q, K, As, Bs, acc, tid);
        float4 c4[4];
#pragma unroll
        for (int i = 0; i < 4; i++)
            c4[i] = *(const float4*)&cstat[b * 4096 + m0 + wm * 64 + i * 16 + quad * 4];
#pragma unroll
        for (int i = 0; i < 4; i++) {
            float cc[4] = {c4[i].x, c4[i].y, c4[i].z, c4[i].w};
#pragma unroll
            for (int rg = 0; rg < 4; rg++) {
                float c = cc[rg];
                float v0 = acc[i][0][rg] - c, v1 = acc[i][1][rg] - c;
                float v2 = acc[i][2][rg] - c, v3 = acc[i][3][rg] - c;
                float vm = fmaxf(fmaxf(v0, v1), fmaxf(v2, v3));
                if (vm > -60.f) {  // see comment above: -60, NOT -30
                    cp0 += fexp2(v0); cp1 += fexp2(v1);
                    cp2 += fexp2(v2); cp3 += fexp2(v3);
                }
            }
        }
    }
    // reduce over quad lanes (bits 4,5 = same column, different rows)
    float cps[4] = {cp0, cp1, cp2, cp3};
#pragma unroll
    for (int j = 0; j < 4; j++) {
        float s = cps[j];
        s += __shfl_xor(s, 16);
        s += __shfl_xor(s, 32);
        if (lane < 16)
            atomicAdd(&Sg[b * 4096 + nblk * 128 + wn * 64 + j * 16 + lane], s);
    }
}

// ---------------------------------------------------------------------------
// Final: out = relu(BN((V*rowscale) . Wo^T + bo)) + X  (fp32 out)
// rowscale S/(1e-9+S) commutes with @Wo (it's a row scale) -> epilogue.
// grid.x spans both batches: m0 in [0,8192) == flat (b,m) for A/Sg/X/out.
// ---------------------------------------------------------------------------
__global__ __launch_bounds__(256) void gemm_final(
    const u16* __restrict__ A, const u16* __restrict__ Bt,
    const float* __restrict__ Sg, const float* __restrict__ bo,
    const float* __restrict__ g, const float* __restrict__ bb,
    const float* __restrict__ mean, const float* __restrict__ var,
    const float* __restrict__ X, float* __restrict__ out) {
    __shared__ __align__(16) u16 As[128 * 32];
    __shared__ __align__(16) u16 Bs[128 * 32];
    int tid = threadIdx.x;
    int m0 = blockIdx.x * 128, n0 = blockIdx.y * 128;
    f32x4 acc[4][4];
#pragma unroll
    for (int i = 0; i < 4; i++)
#pragma unroll
        for (int j = 0; j < 4; j++) acc[i][j] = (f32x4){0.f, 0.f, 0.f, 0.f};
    gemm512(A + (size_t)m0 * 512, Bt + (size_t)n0 * 512, As, Bs, acc, tid);
    int lane = tid & 63, quad = lane >> 4, l15 = lane & 15;
    int wm = tid >> 7, wn = (tid >> 6) & 1;
    float sc[4][4];
#pragma unroll
    for (int i = 0; i < 4; i++) {
        float4 s = *(const float4*)&Sg[m0 + wm * 64 + i * 16 + quad * 4];
        float v[4] = {s.x, s.y, s.z, s.w};
#pragma unroll
        for (int rg = 0; rg < 4; rg++) sc[i][rg] = v[rg] / (1e-9f + v[rg]);
    }
#pragma unroll
    for (int j = 0; j < 4; j++) {
        int n = n0 + wn * 64 + j * 16 + l15;
        float aj = rsqrtf(var[n] + 1e-5f) * g[n];
        float cj = bb[n] - mean[n] * aj;
        float bj = bo[n];
#pragma unroll
        for (int i = 0; i < 4; i++)
#pragma unroll
            for (int rg = 0; rg < 4; rg++) {
                int m = m0 + wm * 64 + i * 16 + quad * 4 + rg;
                float x = acc[i][j][rg] * sc[i][rg] + bj;
                float y = x * aj + cj;
                out[(size_t)m * 512 + n] = fmaxf(y, 0.f) + X[(size_t)m * 512 + n];
            }
    }
}

// ---------------------------------------------------------------------------
extern "C" void kernel_launch(void* const* d_in, const int* in_sizes, int n_in,
                              void* d_out, int out_size, void* d_ws, size_t ws_size,
                              hipStream_t stream) {
    const float* X  = (const float*)d_in[0];
    const float* Wq = (const float*)d_in[1];
    const float* Wk = (const float*)d_in[2];
    const float* Wv = (const float*)d_in[3];
    const float* Wo = (const float*)d_in[4];
    const float* bq = (const float*)d_in[5];
    const float* bk = (const float*)d_in[6];
    const float* bv = (const float*)d_in[7];
    const float* bo = (const float*)d_in[8];
    const float* g    = (const float*)d_in[9];
    const float* bb   = (const float*)d_in[10];
    const float* mean = (const float*)d_in[11];
    const float* var  = (const float*)d_in[12];
    float* out = (float*)d_out;

    char* ws = (char*)d_ws;
    u16* Xb  = (u16*)(ws + 0);                    // 8 MB [B*N, C] bf16
    u16* Wqt = (u16*)(ws + 8388608);              // 3x512KB contiguous
    u16* Wkt = (u16*)(ws + 8912896);
    u16* Wvt = (u16*)(ws + 9437184);
    u16* Wot = (u16*)(ws + 9961472);
    u16* Qb  = (u16*)(ws + 10485760);             // Q,K,V contiguous 3x8MB
    u16* Kb  = (u16*)(ws + 18874368);
    u16* Vb  = (u16*)(ws + 27262976);
    float2* statsP = (float2*)(ws + 35651584);    // [B][16][4096] = 1 MB
    float* cstat   = (float*)(ws + 36700160);     // [B*4096]
    float* Sg      = (float*)(ws + 36765696);     // [B*4096]

    convert_x<<<4096, 256, 0, stream>>>(X, Xb);
    transpose_w<<<dim3(16, 16, 4), dim3(32, 8), 0, stream>>>(
        Wq, Wk, Wv, Wo, Wqt, Wkt, Wvt, Wot);
    gemm_qkv<<<dim3(64, 4, 3), 256, 0, stream>>>(Xb, Wqt, bq, bk, bv, Qb);
    attn_pass1<<<dim3(32, 8, 2), 256, 0, stream>>>(Qb, Kb, statsP);
    reduce_stats<<<32, 256, 0, stream>>>(statsP, cstat);
    hipMemsetAsync(Sg, 0, 2 * 4096 * sizeof(float), stream);
    attn_pass2<<<dim3(32, 8, 2), 256, 0, stream>>>(Qb, Kb, cstat, Sg);
    gemm_final<<<dim3(64, 4), 256, 0, stream>>>(Vb, Wot, Sg, bo, g, bb, mean, var,
                                                X, out);
}

// Round 5
// 234.772 us; speedup vs baseline: 1.6179x; 1.0011x over previous
//
#include <hip/hip_runtime.h>
#include <hip/hip_bf16.h>

typedef unsigned short u16;
typedef __attribute__((ext_vector_type(8))) short short8;
typedef __attribute__((ext_vector_type(4))) float f32x4;

__device__ __forceinline__ u16 f2bf(float f) {
    union { float f; unsigned u; } v; v.f = f;
    unsigned r = v.u + 0x7fffu + ((v.u >> 16) & 1u);
    return (u16)(r >> 16);
}

__device__ __forceinline__ float fexp2(float x) {
#if __has_builtin(__builtin_amdgcn_exp2f)
    return __builtin_amdgcn_exp2f(x);
#else
    return __expf(x * 0.6931471805599453f);
#endif
}

// async 16B global->LDS DMA (m97 pattern). lds base must be wave-uniform;
// each lane deposits at base + lane*16.
__device__ __forceinline__ void async_cp16(const u16* g, u16* l) {
    __builtin_amdgcn_global_load_lds(
        (const __attribute__((address_space(1))) void*)g,
        (__attribute__((address_space(3))) void*)l, 16, 0, 0);
}

// ---------------------------------------------------------------------------
// 128x128x512 MFMA core: A [128,512] bf16 row-major, B^T [128,512] bf16
// row-major (computes A . B^T). 4 waves, each 64x64 (4x4 tiles of 16x16x32).
// LDS tiles UNPADDED [128][32] — required by global_load_lds deposit order.
// ---------------------------------------------------------------------------
__device__ __forceinline__ void gemm512(const u16* __restrict__ A,
                                        const u16* __restrict__ B,
                                        u16* As, u16* Bs,
                                        f32x4 acc[4][4], int tid) {
    const int lane = tid & 63, w = tid >> 6;
    const int quad = lane >> 4, l15 = lane & 15;
    const int wm = tid >> 7, wn = (tid >> 6) & 1;
    const int srow0 = w * 32 + (lane >> 2);
    const int srow1 = srow0 + 16;
    const int scol = (lane & 3) * 8;
    u16* la0 = As + (w * 2 + 0) * 512;
    u16* la1 = As + (w * 2 + 1) * 512;
    u16* lb0 = Bs + (w * 2 + 0) * 512;
    u16* lb1 = Bs + (w * 2 + 1) * 512;
    for (int k0 = 0; k0 < 512; k0 += 32) {
        __syncthreads();
        async_cp16(A + (size_t)srow0 * 512 + k0 + scol, la0);
        async_cp16(A + (size_t)srow1 * 512 + k0 + scol, la1);
        async_cp16(B + (size_t)srow0 * 512 + k0 + scol, lb0);
        async_cp16(B + (size_t)srow1 * 512 + k0 + scol, lb1);
        __syncthreads();
        short8 af[4], bfr[4];
#pragma unroll
        for (int i = 0; i < 4; i++)
            af[i] = *(const short8*)&As[(wm * 64 + i * 16 + l15) * 32 + quad * 8];
#pragma unroll
        for (int j = 0; j < 4; j++)
            bfr[j] = *(const short8*)&Bs[(wn * 64 + j * 16 + l15) * 32 + quad * 8];
#pragma unroll
        for (int i = 0; i < 4; i++)
#pragma unroll
            for (int j = 0; j < 4; j++)
                acc[i][j] = __builtin_amdgcn_mfma_f32_16x16x32_bf16(
                    af[i], bfr[j], acc[i][j], 0, 0, 0);
    }
}

// ---------------------------------------------------------------------------
// 64x128x512 variant (A 64 rows) for gemm_final: grid doubles to 2 blocks/CU.
// 4 waves in 2x2; each wave 32x64 (2x4 tiles). Staging: 3 DMA/wave/k-iter.
// ---------------------------------------------------------------------------
__device__ __forceinline__ void gemm512_r64(const u16* __restrict__ A,
                                            const u16* __restrict__ B,
                                            u16* As, u16* Bs,
                                            f32x4 acc[2][4], int tid) {
    const int lane = tid & 63, w = tid >> 6;
    const int quad = lane >> 4, l15 = lane & 15;
    const int wm = tid >> 7, wn = (tid >> 6) & 1;
    const int srowA = w * 16 + (lane >> 2);
    const int srowB0 = (w * 2 + 0) * 16 + (lane >> 2);
    const int srowB1 = (w * 2 + 1) * 16 + (lane >> 2);
    const int scol = (lane & 3) * 8;
    u16* la = As + w * 512;
    u16* lb0 = Bs + (w * 2 + 0) * 512;
    u16* lb1 = Bs + (w * 2 + 1) * 512;
    for (int k0 = 0; k0 < 512; k0 += 32) {
        __syncthreads();
        async_cp16(A + (size_t)srowA * 512 + k0 + scol, la);
        async_cp16(B + (size_t)srowB0 * 512 + k0 + scol, lb0);
        async_cp16(B + (size_t)srowB1 * 512 + k0 + scol, lb1);
        __syncthreads();
        short8 af[2], bfr[4];
#pragma unroll
        for (int i = 0; i < 2; i++)
            af[i] = *(const short8*)&As[(wm * 32 + i * 16 + l15) * 32 + quad * 8];
#pragma unroll
        for (int j = 0; j < 4; j++)
            bfr[j] = *(const short8*)&Bs[(wn * 64 + j * 16 + l15) * 32 + quad * 8];
#pragma unroll
        for (int i = 0; i < 2; i++)
#pragma unroll
            for (int j = 0; j < 4; j++)
                acc[i][j] = __builtin_amdgcn_mfma_f32_16x16x32_bf16(
                    af[i], bfr[j], acc[i][j], 0, 0, 0);
    }
}

// ---------------------------------------------------------------------------
// Fused prep: blocks [0,4096) convert X->bf16; blocks [4096,5120) transpose
// the four weights to bf16 [out,in]. Independent work, block-uniform branch.
// ---------------------------------------------------------------------------
__global__ void prep(const float* __restrict__ X, const float* __restrict__ W0,
                     const float* __restrict__ W1, const float* __restrict__ W2,
                     const float* __restrict__ W3, u16* __restrict__ Xb,
                     u16* __restrict__ T0, u16* __restrict__ T1,
                     u16* __restrict__ T2, u16* __restrict__ T3) {
    __shared__ float tile[32][33];
    int id = blockIdx.x, tid = threadIdx.x;
    if (id < 4096) {
        int idx = (id * 256 + tid) * 4;
        float4 v = *(const float4*)&X[idx];
        ushort4 o;
        o.x = f2bf(v.x); o.y = f2bf(v.y); o.z = f2bf(v.z); o.w = f2bf(v.w);
        *(ushort4*)&Xb[idx] = o;
        return;
    }
    int t = id - 4096;
    int z = t >> 8, rem = t & 255;
    int bo_ = (rem & 15) * 32, bi = (rem >> 4) * 32;
    const float* src; u16* dst;
    switch (z) {
        case 0: src = W0; dst = T0; break;
        case 1: src = W1; dst = T1; break;
        case 2: src = W2; dst = T2; break;
        default: src = W3; dst = T3; break;
    }
    int tx = tid & 31, ty = tid >> 5;  // (32, 8)
#pragma unroll
    for (int s = 0; s < 4; s++) {
        int i = bi + ty + s * 8;
        tile[ty + s * 8][tx] = src[i * 512 + bo_ + tx];
    }
    __syncthreads();
#pragma unroll
    for (int s = 0; s < 4; s++) {
        int o = bo_ + ty + s * 8;
        dst[o * 512 + bi + tx] = f2bf(tile[tx][ty + s * 8]);
    }
}

// ---------------------------------------------------------------------------
// Fused QKV projection. z==0 (Q) additionally scaled by log2(e) so the
// score GEMMs come out in base-2 domain (exp2 instead of exp).
// ---------------------------------------------------------------------------
__global__ __launch_bounds__(256) void gemm_qkv(
    const u16* __restrict__ Xb, const u16* __restrict__ Wall,
    const float* __restrict__ bq, const float* __restrict__ bk,
    const float* __restrict__ bv, u16* __restrict__ Qall) {
    __shared__ __align__(16) u16 As[128 * 32];
    __shared__ __align__(16) u16 Bs[128 * 32];
    int tid = threadIdx.x;
    int m0 = blockIdx.x * 128, n0 = blockIdx.y * 128, z = blockIdx.z;
    const u16* Bt = Wall + (size_t)z * 262144 + (size_t)n0 * 512;
    const float* bias = (z == 0) ? bq : (z == 1) ? bk : bv;
    const float qs = (z == 0) ? 1.44269504088896340736f : 1.0f;
    u16* C = Qall + (size_t)z * 4194304;
    f32x4 acc[4][4];
#pragma unroll
    for (int i = 0; i < 4; i++)
#pragma unroll
        for (int j = 0; j < 4; j++) acc[i][j] = (f32x4){0.f, 0.f, 0.f, 0.f};
    gemm512(Xb + (size_t)m0 * 512, Bt, As, Bs, acc, tid);
    int lane = tid & 63, quad = lane >> 4, l15 = lane & 15;
    int wm = tid >> 7, wn = (tid >> 6) & 1;
#pragma unroll
    for (int j = 0; j < 4; j++) {
        int n = n0 + wn * 64 + j * 16 + l15;
        float bvv = bias[n];
#pragma unroll
        for (int i = 0; i < 4; i++)
#pragma unroll
            for (int rg = 0; rg < 4; rg++) {
                int m = m0 + wm * 64 + i * 16 + quad * 4 + rg;
                C[(size_t)m * 512 + n] = f2bf((acc[i][j][rg] + bvv) * qs);
            }
    }
}

// ---------------------------------------------------------------------------
// Pass 1: per-row (max, sum 2^x) over an n-chunk of 256 cols.
// Per-thread online state in registers. Skip threshold -30 is safe here:
// a skipped group cannot contain the max, Z loses <4096*2^-30 relative.
// grid (32, 16, 2) = 1024 blocks = 4 blocks/CU.
// ---------------------------------------------------------------------------
__global__ __launch_bounds__(256) void attn_pass1(
    const u16* __restrict__ Qb, const u16* __restrict__ Kb,
    float2* __restrict__ statsP) {
    __shared__ __align__(16) u16 As[128 * 32];
    __shared__ __align__(16) u16 Bs[128 * 32];
    int tid = threadIdx.x;
    int mblk = blockIdx.x, nch = blockIdx.y, b = blockIdx.z;
    const u16* Q = Qb + ((size_t)(b * 4096 + mblk * 128)) * 512;
    int lane = tid & 63, quad = lane >> 4, l15 = lane & 15;
    int wm = tid >> 7, wn = (tid >> 6) & 1;
    float runM[4][4], runL[4][4];
#pragma unroll
    for (int i = 0; i < 4; i++)
#pragma unroll
        for (int rg = 0; rg < 4; rg++) { runM[i][rg] = -INFINITY; runL[i][rg] = 0.f; }
    for (int nt = 0; nt < 2; nt++) {
        const u16* K = Kb + ((size_t)(b * 4096 + nch * 256 + nt * 128)) * 512;
        f32x4 acc[4][4];
#pragma unroll
        for (int i = 0; i < 4; i++)
#pragma unroll
            for (int j = 0; j < 4; j++) acc[i][j] = (f32x4){0.f, 0.f, 0.f, 0.f};
        gemm512(Q, K, As, Bs, acc, tid);
#pragma unroll
        for (int i = 0; i < 4; i++)
#pragma unroll
            for (int rg = 0; rg < 4; rg++) {
                float v0 = acc[i][0][rg], v1 = acc[i][1][rg];
                float v2 = acc[i][2][rg], v3 = acc[i][3][rg];
                float vm = fmaxf(fmaxf(v0, v1), fmaxf(v2, v3));
                float mo = runM[i][rg];
                if (vm > mo - 30.f) {  // else: Z-mass <4*2^-30 rel., M unchanged
                    float nm = fmaxf(mo, vm);
                    runL[i][rg] = runL[i][rg] * fexp2(mo - nm) +
                                  fexp2(v0 - nm) + fexp2(v1 - nm) +
                                  fexp2(v2 - nm) + fexp2(v3 - nm);
                    runM[i][rg] = nm;
                }
            }
    }
    // combine across the 16 l15 lanes: max first (4 shfl), one rescale exp2,
    // then plain sum (4 shfl). runM is finite (first group always processed).
#pragma unroll
    for (int i = 0; i < 4; i++)
#pragma unroll
        for (int rg = 0; rg < 4; rg++) {
            float M = runM[i][rg];
            float Mf = M;
#pragma unroll
            for (int d = 1; d < 16; d <<= 1) Mf = fmaxf(Mf, __shfl_xor(Mf, d));
            float L = runL[i][rg] * fexp2(M - Mf);
#pragma unroll
            for (int d = 1; d < 16; d <<= 1) L += __shfl_xor(L, d);
            if (l15 == 0)
                statsP[((size_t)(b * 32 + nch * 2 + wn)) * 4096 +
                       mblk * 128 + wm * 64 + i * 16 + quad * 4 + rg] =
                    make_float2(Mf, L);
        }
}

// combine the 32 partials per row -> c = M + log2(Z); also zero Sg for pass2.
__global__ void reduce_stats(const float2* __restrict__ statsP,
                             float* __restrict__ cstat, float* __restrict__ Sg) {
    int t = blockIdx.x * 256 + threadIdx.x;  // 0..8191
    int b = t >> 12, m = t & 4095;
    float M = -INFINITY;
    float2 p[32];
#pragma unroll
    for (int ch = 0; ch < 32; ch++) {
        p[ch] = statsP[((size_t)(b * 32 + ch)) * 4096 + m];
        M = fmaxf(M, p[ch].x);
    }
    float L = 0.f;
#pragma unroll
    for (int ch = 0; ch < 32; ch++) L += p[ch].y * fexp2(p[ch].x - M);
    cstat[t] = M + __log2f(L);
    Sg[t] = 0.f;
}

// ---------------------------------------------------------------------------
// Pass 2: recompute scores, accumulate 2^(s-c) into column sums S.
// Column partials live in registers across the whole mt loop.
// SKIP THRESHOLD -60, NOT -30: downstream is scale=S/(1e-9+S), sensitive
// exactly at S~2^-30; dropped mass 4096*2^-60 = 2^-48 << 1e-9.
// grid (32, 16, 2) = 1024 blocks = 4 blocks/CU.
// ---------------------------------------------------------------------------
__global__ __launch_bounds__(256) void attn_pass2(
    const u16* __restrict__ Qb, const u16* __restrict__ Kb,
    const float* __restrict__ cstat, float* __restrict__ Sg) {
    __shared__ __align__(16) u16 As[128 * 32];
    __shared__ __align__(16) u16 Bs[128 * 32];
    int tid = threadIdx.x;
    int nblk = blockIdx.x, mch = blockIdx.y, b = blockIdx.z;
    const u16* K = Kb + ((size_t)(b * 4096 + nblk * 128)) * 512;
    int lane = tid & 63, quad = lane >> 4, l15 = lane & 15;
    int wm = tid >> 7, wn = (tid >> 6) & 1;
    float cp0 = 0.f, cp1 = 0.f, cp2 = 0.f, cp3 = 0.f;
    for (int mt = 0; mt < 2; mt++) {
        int m0 = mch * 256 + mt * 128;
        const u16* Q = Qb + ((size_t)(b * 4096 + m0)) * 512;
        f32x4 acc[4][4];
#pragma unroll
        for (int i = 0; i < 4; i++)
#pragma unroll
            for (int j = 0; j < 4; j++) acc[i][j] = (f32x4){0.f, 0.f, 0.f, 0.f};
        gemm512(Q, K, As, Bs, acc, tid);
        float4 c4[4];
#pragma unroll
        for (int i = 0; i < 4; i++)
            c4[i] = *(const float4*)&cstat[b * 4096 + m0 + wm * 64 + i * 16 + quad * 4];
#pragma unroll
        for (int i = 0; i < 4; i++) {
            float cc[4] = {c4[i].x, c4[i].y, c4[i].z, c4[i].w};
#pragma unroll
            for (int rg = 0; rg < 4; rg++) {
                float c = cc[rg];
                float v0 = acc[i][0][rg] - c, v1 = acc[i][1][rg] - c;
                float v2 = acc[i][2][rg] - c, v3 = acc[i][3][rg] - c;
                float vm = fmaxf(fmaxf(v0, v1), fmaxf(v2, v3));
                if (vm > -60.f) {  // -60, NOT -30 (round-3 lesson)
                    cp0 += fexp2(v0); cp1 += fexp2(v1);
                    cp2 += fexp2(v2); cp3 += fexp2(v3);
                }
            }
        }
    }
    // reduce over quad lanes (bits 4,5 = same column, different rows)
    float cps[4] = {cp0, cp1, cp2, cp3};
#pragma unroll
    for (int j = 0; j < 4; j++) {
        float s = cps[j];
        s += __shfl_xor(s, 16);
        s += __shfl_xor(s, 32);
        if (lane < 16)
            atomicAdd(&Sg[b * 4096 + nblk * 128 + wn * 64 + j * 16 + lane], s);
    }
}

// ---------------------------------------------------------------------------
// Final: out = relu(BN((V*rowscale) . Wo^T + bo)) + X  (fp32 out)
// rowscale S/(1e-9+S) commutes with @Wo (row scale) -> epilogue.
// 64x128 tiles, grid (128, 4) = 512 blocks = 2 blocks/CU.
// grid.x spans both batches: m0 in [0,8192) == flat (b,m) for A/Sg/X/out.
// ---------------------------------------------------------------------------
__global__ __launch_bounds__(256) void gemm_final(
    const u16* __restrict__ A, const u16* __restrict__ Bt,
    const float* __restrict__ Sg, const float* __restrict__ bo,
    const float* __restrict__ g, const float* __restrict__ bb,
    const float* __restrict__ mean, const float* __restrict__ var,
    const float* __restrict__ X, float* __restrict__ out) {
    __shared__ __align__(16) u16 As[64 * 32];
    __shared__ __align__(16) u16 Bs[128 * 32];
    int tid = threadIdx.x;
    int m0 = blockIdx.x * 64, n0 = blockIdx.y * 128;
    f32x4 acc[2][4];
#pragma unroll
    for (int i = 0; i < 2; i++)
#pragma unroll
        for (int j = 0; j < 4; j++) acc[i][j] = (f32x4){0.f, 0.f, 0.f, 0.f};
    gemm512_r64(A + (size_t)m0 * 512, Bt + (size_t)n0 * 512, As, Bs, acc, tid);
    int lane = tid & 63, quad = lane >> 4, l15 = lane & 15;
    int wm = tid >> 7, wn = (tid >> 6) & 1;
    float sc[2][4];
#pragma unroll
    for (int i = 0; i < 2; i++) {
        float4 s = *(const float4*)&Sg[m0 + wm * 32 + i * 16 + quad * 4];
        float v[4] = {s.x, s.y, s.z, s.w};
#pragma unroll
        for (int rg = 0; rg < 4; rg++) sc[i][rg] = v[rg] / (1e-9f + v[rg]);
    }
#pragma unroll
    for (int j = 0; j < 4; j++) {
        int n = n0 + wn * 64 + j * 16 + l15;
        float aj = rsqrtf(var[n] + 1e-5f) * g[n];
        float cj = bb[n] - mean[n] * aj;
        float bj = bo[n];
#pragma unroll
        for (int i = 0; i < 2; i++)
#pragma unroll
            for (int rg = 0; rg < 4; rg++) {
                int m = m0 + wm * 32 + i * 16 + quad * 4 + rg;
                float x = acc[i][j][rg] * sc[i][rg] + bj;
                float y = x * aj + cj;
                out[(size_t)m * 512 + n] = fmaxf(y, 0.f) + X[(size_t)m * 512 + n];
            }
    }
}

// ---------------------------------------------------------------------------
extern "C" void kernel_launch(void* const* d_in, const int* in_sizes, int n_in,
                              void* d_out, int out_size, void* d_ws, size_t ws_size,
                              hipStream_t stream) {
    const float* X  = (const float*)d_in[0];
    const float* Wq = (const float*)d_in[1];
    const float* Wk = (const float*)d_in[2];
    const float* Wv = (const float*)d_in[3];
    const float* Wo = (const float*)d_in[4];
    const float* bq = (const float*)d_in[5];
    const float* bk = (const float*)d_in[6];
    const float* bv = (const float*)d_in[7];
    const float* bo = (const float*)d_in[8];
    const float* g    = (const float*)d_in[9];
    const float* bb   = (const float*)d_in[10];
    const float* mean = (const float*)d_in[11];
    const float* var  = (const float*)d_in[12];
    float* out = (float*)d_out;

    char* ws = (char*)d_ws;
    u16* Xb  = (u16*)(ws + 0);                    // 8 MB [B*N, C] bf16
    u16* Wqt = (u16*)(ws + 8388608);              // 4x512KB contiguous
    u16* Wkt = (u16*)(ws + 8912896);
    u16* Wvt = (u16*)(ws + 9437184);
    u16* Wot = (u16*)(ws + 9961472);
    u16* Qb  = (u16*)(ws + 10485760);             // Q,K,V contiguous 3x8MB
    u16* Kb  = (u16*)(ws + 18874368);
    u16* Vb  = (u16*)(ws + 27262976);
    float2* statsP = (float2*)(ws + 35651584);    // [B][32][4096] = 2 MB
    float* cstat   = (float*)(ws + 37748736);     // [B*4096]
    float* Sg      = (float*)(ws + 37781504);     // [B*4096]

    prep<<<5120, 256, 0, stream>>>(X, Wq, Wk, Wv, Wo, Xb, Wqt, Wkt, Wvt, Wot);
    gemm_qkv<<<dim3(64, 4, 3), 256, 0, stream>>>(Xb, Wqt, bq, bk, bv, Qb);
    attn_pass1<<<dim3(32, 16, 2), 256, 0, stream>>>(Qb, Kb, statsP);
    reduce_stats<<<32, 256, 0, stream>>>(statsP, cstat, Sg);
    attn_pass2<<<dim3(32, 16, 2), 256, 0, stream>>>(Qb, Kb, cstat, Sg);
    gemm_final<<<dim3(128, 4), 256, 0, stream>>>(Vb, Wot, Sg, bo, g, bb, mean, var,
                                                 X, out);
}

// Round 6
// 231.436 us; speedup vs baseline: 1.6412x; 1.0144x over previous
//
#include <hip/hip_runtime.h>
#include <hip/hip_bf16.h>

typedef unsigned short u16;
typedef __attribute__((ext_vector_type(8))) short short8;
typedef __attribute__((ext_vector_type(4))) float f32x4;

__device__ __forceinline__ u16 f2bf(float f) {
    union { float f; unsigned u; } v; v.f = f;
    unsigned r = v.u + 0x7fffu + ((v.u >> 16) & 1u);
    return (u16)(r >> 16);
}

__device__ __forceinline__ float fexp2(float x) {
#if __has_builtin(__builtin_amdgcn_exp2f)
    return __builtin_amdgcn_exp2f(x);
#else
    return __expf(x * 0.6931471805599453f);
#endif
}

// async 16B global->LDS DMA (m97 pattern). lds base must be wave-uniform;
// each lane deposits at base + lane*16.
__device__ __forceinline__ void async_cp16(const u16* g, u16* l) {
    __builtin_amdgcn_global_load_lds(
        (const __attribute__((address_space(1))) void*)g,
        (__attribute__((address_space(3))) void*)l, 16, 0, 0);
}

// ---------------------------------------------------------------------------
// XOR-swizzled LDS GEMM cores.
//
// Unpadded [rows][32] layout has 64B rows = 16 banks: a ds_read_b128 of
// granule G = l15*4+quad hits bank-group G%8 = 4*(l15&1)+quad -> 16 lanes of
// a quad pile 8-deep on 4 banks = 8-way conflict = 2.94x (m136; 4.2M
// SQ_LDS_BANK_CONFLICT every round so far). Fix under global_load_lds's
// contiguous-deposit constraint: permute SOURCE granules. Window = 16 rows =
// 1KB = 64 granules of 16B. Store granule G at position P = G ^ ((G>>3)&7)
// (involution, bits[5:3] fixed). Write: lane l sits at P=l, fetches
// G = l^((l>>3)&7). Read: want G=l15*4+quad -> P = G ^ (l15>>1); bank-group
// (4*(l15&1)+quad)^(l15>>1) covers all 8 groups exactly twice per quad ->
// 2-way = free (m136: 1.02x).
// ---------------------------------------------------------------------------

// 128x128x512: A [128,512] bf16 rm, B^T [128,512] bf16 rm (computes A.B^T).
// 4 waves, each 64x64 (4x4 tiles of 16x16x32).
__device__ __forceinline__ void gemm512(const u16* __restrict__ A,
                                        const u16* __restrict__ B,
                                        u16* As, u16* Bs,
                                        f32x4 acc[4][4], int tid) {
    const int lane = tid & 63, w = tid >> 6;
    const int quad = lane >> 4, l15 = lane & 15;
    const int wm = tid >> 7, wn = (tid >> 6) & 1;
    // write-side swizzle
    const int Gw = lane ^ ((lane >> 3) & 7);
    const int srow = Gw >> 2;          // 0..15 within 16-row window
    const int scol = (Gw & 3) * 8;     // elem offset in row
    const int arow0 = w * 32 + srow, arow1 = arow0 + 16;
    u16* la0 = As + (w * 2 + 0) * 512;
    u16* la1 = As + (w * 2 + 1) * 512;
    u16* lb0 = Bs + (w * 2 + 0) * 512;
    u16* lb1 = Bs + (w * 2 + 1) * 512;
    // read-side swizzled position (elems) within a window
    const int Pr8 = ((l15 * 4 + quad) ^ (l15 >> 1)) * 8;
    for (int k0 = 0; k0 < 512; k0 += 32) {
        __syncthreads();
        async_cp16(A + (size_t)arow0 * 512 + k0 + scol, la0);
        async_cp16(A + (size_t)arow1 * 512 + k0 + scol, la1);
        async_cp16(B + (size_t)arow0 * 512 + k0 + scol, lb0);
        async_cp16(B + (size_t)arow1 * 512 + k0 + scol, lb1);
        __syncthreads();
        short8 af[4], bfr[4];
#pragma unroll
        for (int i = 0; i < 4; i++)
            af[i] = *(const short8*)&As[(wm * 64 + i * 16) * 32 + Pr8];
#pragma unroll
        for (int j = 0; j < 4; j++)
            bfr[j] = *(const short8*)&Bs[(wn * 64 + j * 16) * 32 + Pr8];
#pragma unroll
        for (int i = 0; i < 4; i++)
#pragma unroll
            for (int j = 0; j < 4; j++)
                acc[i][j] = __builtin_amdgcn_mfma_f32_16x16x32_bf16(
                    af[i], bfr[j], acc[i][j], 0, 0, 0);
    }
}

// 64x128x512 variant (A 64 rows) for gemm_final. 4 waves in 2x2; each wave
// 32x64 (2x4 tiles). Staging: 3 DMA/wave/k-iter. Same swizzle.
__device__ __forceinline__ void gemm512_r64(const u16* __restrict__ A,
                                            const u16* __restrict__ B,
                                            u16* As, u16* Bs,
                                            f32x4 acc[2][4], int tid) {
    const int lane = tid & 63, w = tid >> 6;
    const int quad = lane >> 4, l15 = lane & 15;
    const int wm = tid >> 7, wn = (tid >> 6) & 1;
    const int Gw = lane ^ ((lane >> 3) & 7);
    const int srow = Gw >> 2;
    const int scol = (Gw & 3) * 8;
    const int arowA = w * 16 + srow;
    const int arowB0 = (w * 2 + 0) * 16 + srow;
    const int arowB1 = (w * 2 + 1) * 16 + srow;
    u16* la = As + w * 512;
    u16* lb0 = Bs + (w * 2 + 0) * 512;
    u16* lb1 = Bs + (w * 2 + 1) * 512;
    const int Pr8 = ((l15 * 4 + quad) ^ (l15 >> 1)) * 8;
    for (int k0 = 0; k0 < 512; k0 += 32) {
        __syncthreads();
        async_cp16(A + (size_t)arowA * 512 + k0 + scol, la);
        async_cp16(B + (size_t)arowB0 * 512 + k0 + scol, lb0);
        async_cp16(B + (size_t)arowB1 * 512 + k0 + scol, lb1);
        __syncthreads();
        short8 af[2], bfr[4];
#pragma unroll
        for (int i = 0; i < 2; i++)
            af[i] = *(const short8*)&As[(wm * 32 + i * 16) * 32 + Pr8];
#pragma unroll
        for (int j = 0; j < 4; j++)
            bfr[j] = *(const short8*)&Bs[(wn * 64 + j * 16) * 32 + Pr8];
#pragma unroll
        for (int i = 0; i < 2; i++)
#pragma unroll
            for (int j = 0; j < 4; j++)
                acc[i][j] = __builtin_amdgcn_mfma_f32_16x16x32_bf16(
                    af[i], bfr[j], acc[i][j], 0, 0, 0);
    }
}

// ---------------------------------------------------------------------------
// Fused prep: blocks [0,4096) convert X->bf16; blocks [4096,5120) transpose
// the four weights to bf16 [out,in]. Independent work, block-uniform branch.
// ---------------------------------------------------------------------------
__global__ void prep(const float* __restrict__ X, const float* __restrict__ W0,
                     const float* __restrict__ W1, const float* __restrict__ W2,
                     const float* __restrict__ W3, u16* __restrict__ Xb,
                     u16* __restrict__ T0, u16* __restrict__ T1,
                     u16* __restrict__ T2, u16* __restrict__ T3) {
    __shared__ float tile[32][33];
    int id = blockIdx.x, tid = threadIdx.x;
    if (id < 4096) {
        int idx = (id * 256 + tid) * 4;
        float4 v = *(const float4*)&X[idx];
        ushort4 o;
        o.x = f2bf(v.x); o.y = f2bf(v.y); o.z = f2bf(v.z); o.w = f2bf(v.w);
        *(ushort4*)&Xb[idx] = o;
        return;
    }
    int t = id - 4096;
    int z = t >> 8, rem = t & 255;
    int bo_ = (rem & 15) * 32, bi = (rem >> 4) * 32;
    const float* src; u16* dst;
    switch (z) {
        case 0: src = W0; dst = T0; break;
        case 1: src = W1; dst = T1; break;
        case 2: src = W2; dst = T2; break;
        default: src = W3; dst = T3; break;
    }
    int tx = tid & 31, ty = tid >> 5;  // (32, 8)
#pragma unroll
    for (int s = 0; s < 4; s++) {
        int i = bi + ty + s * 8;
        tile[ty + s * 8][tx] = src[i * 512 + bo_ + tx];
    }
    __syncthreads();
#pragma unroll
    for (int s = 0; s < 4; s++) {
        int o = bo_ + ty + s * 8;
        dst[o * 512 + bi + tx] = f2bf(tile[tx][ty + s * 8]);
    }
}

// ---------------------------------------------------------------------------
// Fused QKV projection. z==0 (Q) additionally scaled by log2(e) so the
// score GEMMs come out in base-2 domain (exp2 instead of exp).
// ---------------------------------------------------------------------------
__global__ __launch_bounds__(256) void gemm_qkv(
    const u16* __restrict__ Xb, const u16* __restrict__ Wall,
    const float* __restrict__ bq, const float* __restrict__ bk,
    const float* __restrict__ bv, u16* __restrict__ Qall) {
    __shared__ __align__(16) u16 As[128 * 32];
    __shared__ __align__(16) u16 Bs[128 * 32];
    int tid = threadIdx.x;
    int m0 = blockIdx.x * 128, n0 = blockIdx.y * 128, z = blockIdx.z;
    const u16* Bt = Wall + (size_t)z * 262144 + (size_t)n0 * 512;
    const float* bias = (z == 0) ? bq : (z == 1) ? bk : bv;
    const float qs = (z == 0) ? 1.44269504088896340736f : 1.0f;
    u16* C = Qall + (size_t)z * 4194304;
    f32x4 acc[4][4];
#pragma unroll
    for (int i = 0; i < 4; i++)
#pragma unroll
        for (int j = 0; j < 4; j++) acc[i][j] = (f32x4){0.f, 0.f, 0.f, 0.f};
    gemm512(Xb + (size_t)m0 * 512, Bt, As, Bs, acc, tid);
    int lane = tid & 63, quad = lane >> 4, l15 = lane & 15;
    int wm = tid >> 7, wn = (tid >> 6) & 1;
#pragma unroll
    for (int j = 0; j < 4; j++) {
        int n = n0 + wn * 64 + j * 16 + l15;
        float bvv = bias[n];
#pragma unroll
        for (int i = 0; i < 4; i++)
#pragma unroll
            for (int rg = 0; rg < 4; rg++) {
                int m = m0 + wm * 64 + i * 16 + quad * 4 + rg;
                C[(size_t)m * 512 + n] = f2bf((acc[i][j][rg] + bvv) * qs);
            }
    }
}

// ---------------------------------------------------------------------------
// Pass 1: per-row (max, sum 2^x) over an n-chunk of 256 cols.
// Per-thread online state in registers. Skip threshold -30 is safe here:
// a skipped group cannot contain the max, Z loses <4096*2^-30 relative.
// grid (32, 16, 2) = 1024 blocks = 4 blocks/CU.
// ---------------------------------------------------------------------------
__global__ __launch_bounds__(256) void attn_pass1(
    const u16* __restrict__ Qb, const u16* __restrict__ Kb,
    float2* __restrict__ statsP) {
    __shared__ __align__(16) u16 As[128 * 32];
    __shared__ __align__(16) u16 Bs[128 * 32];
    int tid = threadIdx.x;
    int mblk = blockIdx.x, nch = blockIdx.y, b = blockIdx.z;
    const u16* Q = Qb + ((size_t)(b * 4096 + mblk * 128)) * 512;
    int lane = tid & 63, quad = lane >> 4, l15 = lane & 15;
    int wm = tid >> 7, wn = (tid >> 6) & 1;
    float runM[4][4], runL[4][4];
#pragma unroll
    for (int i = 0; i < 4; i++)
#pragma unroll
        for (int rg = 0; rg < 4; rg++) { runM[i][rg] = -INFINITY; runL[i][rg] = 0.f; }
    for (int nt = 0; nt < 2; nt++) {
        const u16* K = Kb + ((size_t)(b * 4096 + nch * 256 + nt * 128)) * 512;
        f32x4 acc[4][4];
#pragma unroll
        for (int i = 0; i < 4; i++)
#pragma unroll
            for (int j = 0; j < 4; j++) acc[i][j] = (f32x4){0.f, 0.f, 0.f, 0.f};
        gemm512(Q, K, As, Bs, acc, tid);
#pragma unroll
        for (int i = 0; i < 4; i++)
#pragma unroll
            for (int rg = 0; rg < 4; rg++) {
                float v0 = acc[i][0][rg], v1 = acc[i][1][rg];
                float v2 = acc[i][2][rg], v3 = acc[i][3][rg];
                float vm = fmaxf(fmaxf(v0, v1), fmaxf(v2, v3));
                float mo = runM[i][rg];
                if (vm > mo - 30.f) {  // else: Z-mass <4*2^-30 rel., M unchanged
                    float nm = fmaxf(mo, vm);
                    runL[i][rg] = runL[i][rg] * fexp2(mo - nm) +
                                  fexp2(v0 - nm) + fexp2(v1 - nm) +
                                  fexp2(v2 - nm) + fexp2(v3 - nm);
                    runM[i][rg] = nm;
                }
            }
    }
    // combine across the 16 l15 lanes: max first (4 shfl), one rescale exp2,
    // then plain sum (4 shfl). runM is finite (first group always processed).
#pragma unroll
    for (int i = 0; i < 4; i++)
#pragma unroll
        for (int rg = 0; rg < 4; rg++) {
            float M = runM[i][rg];
            float Mf = M;
#pragma unroll
            for (int d = 1; d < 16; d <<= 1) Mf = fmaxf(Mf, __shfl_xor(Mf, d));
            float L = runL[i][rg] * fexp2(M - Mf);
#pragma unroll
            for (int d = 1; d < 16; d <<= 1) L += __shfl_xor(L, d);
            if (l15 == 0)
                statsP[((size_t)(b * 32 + nch * 2 + wn)) * 4096 +
                       mblk * 128 + wm * 64 + i * 16 + quad * 4 + rg] =
                    make_float2(Mf, L);
        }
}

// combine the 32 partials per row -> c = M + log2(Z); also zero Sg for pass2.
__global__ void reduce_stats(const float2* __restrict__ statsP,
                             float* __restrict__ cstat, float* __restrict__ Sg) {
    int t = blockIdx.x * 256 + threadIdx.x;  // 0..8191
    int b = t >> 12, m = t & 4095;
    float M = -INFINITY;
    float2 p[32];
#pragma unroll
    for (int ch = 0; ch < 32; ch++) {
        p[ch] = statsP[((size_t)(b * 32 + ch)) * 4096 + m];
        M = fmaxf(M, p[ch].x);
    }
    float L = 0.f;
#pragma unroll
    for (int ch = 0; ch < 32; ch++) L += p[ch].y * fexp2(p[ch].x - M);
    cstat[t] = M + __log2f(L);
    Sg[t] = 0.f;
}

// ---------------------------------------------------------------------------
// Pass 2: recompute scores, accumulate 2^(s-c) into column sums S.
// Column partials live in registers across the whole mt loop.
// SKIP THRESHOLD -60, NOT -30: downstream is scale=S/(1e-9+S), sensitive
// exactly at S~2^-30; dropped mass 4096*2^-60 = 2^-48 << 1e-9.
// grid (32, 16, 2) = 1024 blocks = 4 blocks/CU.
// ---------------------------------------------------------------------------
__global__ __launch_bounds__(256) void attn_pass2(
    const u16* __restrict__ Qb, const u16* __restrict__ Kb,
    const float* __restrict__ cstat, float* __restrict__ Sg) {
    __shared__ __align__(16) u16 As[128 * 32];
    __shared__ __align__(16) u16 Bs[128 * 32];
    int tid = threadIdx.x;
    int nblk = blockIdx.x, mch = blockIdx.y, b = blockIdx.z;
    const u16* K = Kb + ((size_t)(b * 4096 + nblk * 128)) * 512;
    int lane = tid & 63, quad = lane >> 4, l15 = lane & 15;
    int wm = tid >> 7, wn = (tid >> 6) & 1;
    float cp0 = 0.f, cp1 = 0.f, cp2 = 0.f, cp3 = 0.f;
    for (int mt = 0; mt < 2; mt++) {
        int m0 = mch * 256 + mt * 128;
        const u16* Q = Qb + ((size_t)(b * 4096 + m0)) * 512;
        f32x4 acc[4][4];
#pragma unroll
        for (int i = 0; i < 4; i++)
#pragma unroll
            for (int j = 0; j < 4; j++) acc[i][j] = (f32x4){0.f, 0.f, 0.f, 0.f};
        gemm512(Q, K, As, Bs, acc, tid);
        float4 c4[4];
#pragma unroll
        for (int i = 0; i < 4; i++)
            c4[i] = *(const float4*)&cstat[b * 4096 + m0 + wm * 64 + i * 16 + quad * 4];
#pragma unroll
        for (int i = 0; i < 4; i++) {
            float cc[4] = {c4[i].x, c4[i].y, c4[i].z, c4[i].w};
#pragma unroll
            for (int rg = 0; rg < 4; rg++) {
                float c = cc[rg];
                float v0 = acc[i][0][rg] - c, v1 = acc[i][1][rg] - c;
                float v2 = acc[i][2][rg] - c, v3 = acc[i][3][rg] - c;
                float vm = fmaxf(fmaxf(v0, v1), fmaxf(v2, v3));
                if (vm > -60.f) {  // -60, NOT -30 (round-3 lesson)
                    cp0 += fexp2(v0); cp1 += fexp2(v1);
                    cp2 += fexp2(v2); cp3 += fexp2(v3);
                }
            }
        }
    }
    // reduce over quad lanes (bits 4,5 = same column, different rows)
    float cps[4] = {cp0, cp1, cp2, cp3};
#pragma unroll
    for (int j = 0; j < 4; j++) {
        float s = cps[j];
        s += __shfl_xor(s, 16);
        s += __shfl_xor(s, 32);
        if (lane < 16)
            atomicAdd(&Sg[b * 4096 + nblk * 128 + wn * 64 + j * 16 + lane], s);
    }
}

// ---------------------------------------------------------------------------
// Final: out = relu(BN((V*rowscale) . Wo^T + bo)) + X  (fp32 out)
// rowscale S/(1e-9+S) commutes with @Wo (row scale) -> epilogue.
// 64x128 tiles, grid (128, 4) = 512 blocks = 2 blocks/CU.
// grid.x spans both batches: m0 in [0,8192) == flat (b,m) for A/Sg/X/out.
// ---------------------------------------------------------------------------
__global__ __launch_bounds__(256) void gemm_final(
    const u16* __restrict__ A, const u16* __restrict__ Bt,
    const float* __restrict__ Sg, const float* __restrict__ bo,
    const float* __restrict__ g, const float* __restrict__ bb,
    const float* __restrict__ mean, const float* __restrict__ var,
    const float* __restrict__ X, float* __restrict__ out) {
    __shared__ __align__(16) u16 As[64 * 32];
    __shared__ __align__(16) u16 Bs[128 * 32];
    int tid = threadIdx.x;
    int m0 = blockIdx.x * 64, n0 = blockIdx.y * 128;
    f32x4 acc[2][4];
#pragma unroll
    for (int i = 0; i < 2; i++)
#pragma unroll
        for (int j = 0; j < 4; j++) acc[i][j] = (f32x4){0.f, 0.f, 0.f, 0.f};
    gemm512_r64(A + (size_t)m0 * 512, Bt + (size_t)n0 * 512, As, Bs, acc, tid);
    int lane = tid & 63, quad = lane >> 4, l15 = lane & 15;
    int wm = tid >> 7, wn = (tid >> 6) & 1;
    float sc[2][4];
#pragma unroll
    for (int i = 0; i < 2; i++) {
        float4 s = *(const float4*)&Sg[m0 + wm * 32 + i * 16 + quad * 4];
        float v[4] = {s.x, s.y, s.z, s.w};
#pragma unroll
        for (int rg = 0; rg < 4; rg++) sc[i][rg] = v[rg] / (1e-9f + v[rg]);
    }
#pragma unroll
    for (int j = 0; j < 4; j++) {
        int n = n0 + wn * 64 + j * 16 + l15;
        float aj = rsqrtf(var[n] + 1e-5f) * g[n];
        float cj = bb[n] - mean[n] * aj;
        float bj = bo[n];
#pragma unroll
        for (int i = 0; i < 2; i++)
#pragma unroll
            for (int rg = 0; rg < 4; rg++) {
                int m = m0 + wm * 32 + i * 16 + quad * 4 + rg;
                float x = acc[i][j][rg] * sc[i][rg] + bj;
                float y = x * aj + cj;
                out[(size_t)m * 512 + n] = fmaxf(y, 0.f) + X[(size_t)m * 512 + n];
            }
    }
}

// ---------------------------------------------------------------------------
extern "C" void kernel_launch(void* const* d_in, const int* in_sizes, int n_in,
                              void* d_out, int out_size, void* d_ws, size_t ws_size,
                              hipStream_t stream) {
    const float* X  = (const float*)d_in[0];
    const float* Wq = (const float*)d_in[1];
    const float* Wk = (const float*)d_in[2];
    const float* Wv = (const float*)d_in[3];
    const float* Wo = (const float*)d_in[4];
    const float* bq = (const float*)d_in[5];
    const float* bk = (const float*)d_in[6];
    const float* bv = (const float*)d_in[7];
    const float* bo = (const float*)d_in[8];
    const float* g    = (const float*)d_in[9];
    const float* bb   = (const float*)d_in[10];
    const float* mean = (const float*)d_in[11];
    const float* var  = (const float*)d_in[12];
    float* out = (float*)d_out;

    char* ws = (char*)d_ws;
    u16* Xb  = (u16*)(ws + 0);                    // 8 MB [B*N, C] bf16
    u16* Wqt = (u16*)(ws + 8388608);              // 4x512KB contiguous
    u16* Wkt = (u16*)(ws + 8912896);
    u16* Wvt = (u16*)(ws + 9437184);
    u16* Wot = (u16*)(ws + 9961472);
    u16* Qb  = (u16*)(ws + 10485760);             // Q,K,V contiguous 3x8MB
    u16* Kb  = (u16*)(ws + 18874368);
    u16* Vb  = (u16*)(ws + 27262976);
    float2* statsP = (float2*)(ws + 35651584);    // [B][32][4096] = 2 MB
    float* cstat   = (float*)(ws + 37748736);     // [B*4096]
    float* Sg      = (float*)(ws + 37781504);     // [B*4096]

    prep<<<5120, 256, 0, stream>>>(X, Wq, Wk, Wv, Wo, Xb, Wqt, Wkt, Wvt, Wot);
    gemm_qkv<<<dim3(64, 4, 3), 256, 0, stream>>>(Xb, Wqt, bq, bk, bv, Qb);
    attn_pass1<<<dim3(32, 16, 2), 256, 0, stream>>>(Qb, Kb, statsP);
    reduce_stats<<<32, 256, 0, stream>>>(statsP, cstat, Sg);
    attn_pass2<<<dim3(32, 16, 2), 256, 0, stream>>>(Qb, Kb, cstat, Sg);
    gemm_final<<<dim3(128, 4), 256, 0, stream>>>(Vb, Wot, Sg, bo, g, bb, mean, var,
                                                 X, out);
}